// Round 1
// baseline (589.178 us; speedup 1.0000x reference)
//
#include <hip/hip_runtime.h>

#define B_SZ   512
#define N_IN   1024
#define N_MID  8192
#define N_OUT  1000
#define FANIN  64
#define SPLITK 4

// ---------------------------------------------------------------------------
// GEMM1: C[m,n] = relu( sum_k A[m,k] * X[n,k] + bias[m] )
// A: (M,K) row-major (W_in), X: (N,K) row-major (x), C: (M,N) row-major (h^T)
// 64x64 tile, BK=16, 256 threads, 4x4 per thread.
// ---------------------------------------------------------------------------
__global__ __launch_bounds__(256)
void gemm_nt_bias_relu(const float* __restrict__ A,
                       const float* __restrict__ X,
                       const float* __restrict__ bias,
                       float* __restrict__ C,
                       int M, int N, int K)
{
    __shared__ float As[16][68];   // k-major, stride 68 -> <=2-way bank alias
    __shared__ float Xs[16][68];

    const int t   = threadIdx.x;
    const int m0  = blockIdx.x * 64;
    const int n0  = blockIdx.y * 64;
    const int row = t >> 2;        // 0..63
    const int q   = t & 3;         // 0..3
    const int ty  = t >> 4;        // 0..15
    const int tx  = t & 15;        // 0..15

    const float* Ap = A + (size_t)(m0 + row) * K + 4 * q;
    const float* Xp = X + (size_t)(n0 + row) * K + 4 * q;

    float c[4][4] = {};

    for (int k0 = 0; k0 < K; k0 += 16) {
        const float4 av = *(const float4*)(Ap + k0);
        const float4 xv = *(const float4*)(Xp + k0);
        __syncthreads();
        As[4*q+0][row] = av.x; As[4*q+1][row] = av.y;
        As[4*q+2][row] = av.z; As[4*q+3][row] = av.w;
        Xs[4*q+0][row] = xv.x; Xs[4*q+1][row] = xv.y;
        Xs[4*q+2][row] = xv.z; Xs[4*q+3][row] = xv.w;
        __syncthreads();
        #pragma unroll
        for (int kk = 0; kk < 16; ++kk) {
            const float4 a = *(const float4*)&As[kk][4*ty];
            const float4 b = *(const float4*)&Xs[kk][4*tx];
            const float ar[4] = {a.x, a.y, a.z, a.w};
            const float br[4] = {b.x, b.y, b.z, b.w};
            #pragma unroll
            for (int i = 0; i < 4; ++i)
                #pragma unroll
                for (int j = 0; j < 4; ++j)
                    c[i][j] += ar[i] * br[j];
        }
    }

    #pragma unroll
    for (int i = 0; i < 4; ++i) {
        const int m = m0 + 4*ty + i;
        const float bb = bias[m];
        float4 o;
        o.x = fmaxf(c[i][0] + bb, 0.f);
        o.y = fmaxf(c[i][1] + bb, 0.f);
        o.z = fmaxf(c[i][2] + bb, 0.f);
        o.w = fmaxf(c[i][3] + bb, 0.f);
        *(float4*)&C[(size_t)m * N + n0 + 4*tx] = o;
    }
}

// ---------------------------------------------------------------------------
// Condensed layer: out[o,b] = relu( sum_f W[o,f] * h[idx[o,f], b] + bm[o] )
// h, out: (N_MID, B_SZ) row-major. One block per o, 256 threads, float2 over b.
// ---------------------------------------------------------------------------
__global__ __launch_bounds__(256)
void condensed_relu(const float* __restrict__ h,
                    const int*   __restrict__ idx,  // (N_MID, FANIN)
                    const float* __restrict__ W,    // (N_MID, FANIN)
                    const float* __restrict__ bm,   // (N_MID)
                    float* __restrict__ out)
{
    __shared__ int   sIdx[FANIN];
    __shared__ float sW[FANIN];

    const int o = blockIdx.x;
    const int t = threadIdx.x;

    if (t < FANIN) {
        sIdx[t] = idx[(size_t)o * FANIN + t];
        sW[t]   = W[(size_t)o * FANIN + t];
    }
    __syncthreads();

    float2 acc = {0.f, 0.f};
    #pragma unroll 8
    for (int f = 0; f < FANIN; ++f) {
        const int   j = sIdx[f];
        const float w = sW[f];
        const float2 hv = *(const float2*)&h[(size_t)j * B_SZ + 2 * t];
        acc.x += w * hv.x;
        acc.y += w * hv.y;
    }
    const float bb = bm[o];
    acc.x = fmaxf(acc.x + bb, 0.f);
    acc.y = fmaxf(acc.y + bb, 0.f);
    *(float2*)&out[(size_t)o * B_SZ + 2 * t] = acc;
}

// ---------------------------------------------------------------------------
// GEMM3 (split-K): P[s,b,n] = sum_{k in slice s} Wout[n,k] * h[k,b]
// Wout: (N_OUT, K) row-major, h: (K, B_SZ) row-major (k-major!).
// grid: (16 n-tiles, 8 b-tiles, SPLITK). 64x64 tile, 4x4 per thread.
// ---------------------------------------------------------------------------
__global__ __launch_bounds__(256)
void gemm3_splitk(const float* __restrict__ Wout,
                  const float* __restrict__ h,
                  float* __restrict__ P)
{
    __shared__ float Ws[16][68];
    __shared__ float Hs[16][68];

    const int t   = threadIdx.x;
    const int n0  = blockIdx.x * 64;
    const int b0  = blockIdx.y * 64;
    const int s   = blockIdx.z;
    const int row = t >> 2;        // 0..63
    const int q   = t & 3;         // 0..3
    const int kq  = t >> 4;        // 0..15 (for Hs loads)
    const int c4  = t & 15;        // 0..15
    const int ty  = t >> 4;        // 0..15 -> b direction
    const int tx  = t & 15;        // 0..15 -> n direction

    const int nrow = (n0 + row < N_OUT) ? (n0 + row) : (N_OUT - 1);
    const float* Wp = Wout + (size_t)nrow * N_MID + 4 * q;

    const int kBeg = s * (N_MID / SPLITK);
    const int kEnd = kBeg + (N_MID / SPLITK);

    float c[4][4] = {};

    for (int k0 = kBeg; k0 < kEnd; k0 += 16) {
        const float4 wv = *(const float4*)(Wp + k0);
        const float4 hv = *(const float4*)&h[(size_t)(k0 + kq) * B_SZ + b0 + 4 * c4];
        __syncthreads();
        Ws[4*q+0][row] = wv.x; Ws[4*q+1][row] = wv.y;
        Ws[4*q+2][row] = wv.z; Ws[4*q+3][row] = wv.w;
        *(float4*)&Hs[kq][4*c4] = hv;
        __syncthreads();
        #pragma unroll
        for (int kk = 0; kk < 16; ++kk) {
            const float4 hh = *(const float4*)&Hs[kk][4*ty];
            const float4 ww = *(const float4*)&Ws[kk][4*tx];
            const float hr[4] = {hh.x, hh.y, hh.z, hh.w};
            const float wr[4] = {ww.x, ww.y, ww.z, ww.w};
            #pragma unroll
            for (int i = 0; i < 4; ++i)
                #pragma unroll
                for (int j = 0; j < 4; ++j)
                    c[i][j] += hr[i] * wr[j];
        }
    }

    if (n0 + 4*tx < N_OUT) {   // N_OUT % 4 == 0 -> float4 fully in or out
        #pragma unroll
        for (int i = 0; i < 4; ++i) {
            const int b = b0 + 4*ty + i;
            float4 o;
            o.x = c[i][0]; o.y = c[i][1]; o.z = c[i][2]; o.w = c[i][3];
            *(float4*)&P[((size_t)s * B_SZ + b) * N_OUT + n0 + 4*tx] = o;
        }
    }
}

// ---------------------------------------------------------------------------
// Reduce split-K partials + bias: y[b,n] = sum_s P[s,b,n] + b_out[n]
// ---------------------------------------------------------------------------
__global__ __launch_bounds__(256)
void reduce_out(const float* __restrict__ P,
                const float* __restrict__ b_out,
                float* __restrict__ y)
{
    const int i = blockIdx.x * 256 + threadIdx.x;     // float4 index
    if (i >= (B_SZ * N_OUT) / 4) return;
    const int e = i * 4;
    const int b = e / N_OUT;
    const int n = e - b * N_OUT;                      // multiple of 4

    float4 acc = *(const float4*)&b_out[n];
    #pragma unroll
    for (int s = 0; s < SPLITK; ++s) {
        const float4 p = *(const float4*)&P[((size_t)s * B_SZ + b) * N_OUT + n];
        acc.x += p.x; acc.y += p.y; acc.z += p.z; acc.w += p.w;
    }
    *(float4*)&y[e] = acc;
}

// ---------------------------------------------------------------------------
extern "C" void kernel_launch(void* const* d_in, const int* in_sizes, int n_in,
                              void* d_out, int out_size, void* d_ws, size_t ws_size,
                              hipStream_t stream)
{
    const float* x      = (const float*)d_in[0];  // (512, 1024)
    const float* W_in   = (const float*)d_in[1];  // (8192, 1024)
    const float* b_in   = (const float*)d_in[2];  // (8192)
    const float* W_mid  = (const float*)d_in[3];  // (2, 8192, 64)
    const float* b_mid  = (const float*)d_in[4];  // (2, 8192)
    const float* W_out  = (const float*)d_in[5];  // (1000, 8192)
    const float* b_out  = (const float*)d_in[6];  // (1000)
    const int*   indx   = (const int*)d_in[7];    // (8192, 64)

    float* y  = (float*)d_out;                    // (512, 1000)

    float* h0 = (float*)d_ws;                     // (8192, 512) 16 MB
    float* h1 = h0 + (size_t)N_MID * B_SZ;        // (8192, 512) 16 MB
    float* P  = h1 + (size_t)N_MID * B_SZ;        // (SPLITK, 512, 1000) 8 MB

    // Layer 1: h0[m,b] = relu(x @ W_in.T + b_in)^T
    dim3 g1(N_MID / 64, B_SZ / 64);
    gemm_nt_bias_relu<<<g1, 256, 0, stream>>>(W_in, x, b_in, h0, N_MID, B_SZ, N_IN);

    // Layer 2: condensed i=0: h0 -> h1
    condensed_relu<<<N_MID, 256, 0, stream>>>(h0, indx, W_mid, b_mid, h1);

    // Layer 3: condensed i=1: h1 -> h0
    condensed_relu<<<N_MID, 256, 0, stream>>>(h1, indx,
                                              W_mid + (size_t)N_MID * FANIN,
                                              b_mid + N_MID, h0);

    // Layer 4: y = h0^T @ W_out.T + b_out  (split-K + reduce)
    dim3 g3((N_OUT + 63) / 64, B_SZ / 64, SPLITK);
    gemm3_splitk<<<g3, 256, 0, stream>>>(W_out, h0, P);
    reduce_out<<<(B_SZ * N_OUT / 4 + 255) / 256, 256, 0, stream>>>(P, b_out, y);
}

// Round 3
// 452.768 us; speedup vs baseline: 1.3013x; 1.3013x over previous
//
#include <hip/hip_runtime.h>

#define B_SZ   512
#define N_IN   1024
#define N_MID  8192
#define N_OUT  1000
#define N_OUTP 1024          // padded
#define FANIN  64
#define SPLITK 8

typedef __attribute__((ext_vector_type(8))) short bf16x8;
typedef __attribute__((ext_vector_type(4))) float f32x4;

static __device__ __forceinline__ unsigned short f2bf(float f) {
    unsigned u = __float_as_uint(f);
    unsigned r = u + 0x7FFF + ((u >> 16) & 1);   // round-to-nearest-even
    return (unsigned short)(r >> 16);
}
static __device__ __forceinline__ float bf2f(unsigned short h) {
    return __uint_as_float(((unsigned)h) << 16);
}

// ---------------------------------------------------------------------------
// Convert fp32 (R x K, row-major, K-inner) -> hi/lo bf16 in MFMA fragment
// order. Fragment (mt,kt) covers rows mt*16..+15, k kt*32..+31.
// Slot: lane l holds (m = mt*16 + (l&15), k = kt*32 + (l>>4)*8 + j), j=0..7.
// Buffer: frag fid = mt*KT + kt at dhi[fid*512 + lane*8 + j].
// Rows >= R are zero-padded.
// ---------------------------------------------------------------------------
__global__ __launch_bounds__(256)
void conv_nt(const float* __restrict__ src, int R, int K, int KT,
             short* __restrict__ dhi, short* __restrict__ dlo, int nfrag)
{
    const int wid = threadIdx.x >> 6, lane = threadIdx.x & 63;
    const int fid = blockIdx.x * 4 + wid;
    if (fid >= nfrag) return;
    const int mt = fid / KT, kt = fid - mt * KT;
    const int m = mt * 16 + (lane & 15);
    const int k = kt * 32 + (lane >> 4) * 8;

    float v[8];
    if (m < R) {
        const float4 a = *(const float4*)(src + (size_t)m * K + k);
        const float4 b = *(const float4*)(src + (size_t)m * K + k + 4);
        v[0]=a.x; v[1]=a.y; v[2]=a.z; v[3]=a.w;
        v[4]=b.x; v[5]=b.y; v[6]=b.z; v[7]=b.w;
    } else {
        #pragma unroll
        for (int j = 0; j < 8; ++j) v[j] = 0.f;
    }
    bf16x8 vh, vl;
    #pragma unroll
    for (int j = 0; j < 8; ++j) {
        const unsigned short h = f2bf(v[j]);
        vh[j] = (short)h;
        vl[j] = (short)f2bf(v[j] - bf2f(h));
    }
    const size_t off = (size_t)fid * 512 + lane * 8;
    *(bf16x8*)(dhi + off) = vh;
    *(bf16x8*)(dlo + off) = vl;
}

// ---------------------------------------------------------------------------
// Transposing variant: src is (K x Bcols) fp32 (k-major); produce fragments of
// src^T (Bcols x K). Frag (bt,kt): lane holds (b = bt*16+(l&15),
// k = kt*32+(l>>4)*8+j).
// ---------------------------------------------------------------------------
__global__ __launch_bounds__(256)
void conv_t(const float* __restrict__ src, int Bc, int KT,
            short* __restrict__ dhi, short* __restrict__ dlo, int nfrag)
{
    const int wid = threadIdx.x >> 6, lane = threadIdx.x & 63;
    const int fid = blockIdx.x * 4 + wid;
    if (fid >= nfrag) return;
    const int bt = fid / KT, kt = fid - bt * KT;
    const int b = bt * 16 + (lane & 15);
    const int k = kt * 32 + (lane >> 4) * 8;

    bf16x8 vh, vl;
    #pragma unroll
    for (int j = 0; j < 8; ++j) {
        const float v = src[(size_t)(k + j) * Bc + b];
        const unsigned short h = f2bf(v);
        vh[j] = (short)h;
        vl[j] = (short)f2bf(v - bf2f(h));
    }
    const size_t off = (size_t)fid * 512 + lane * 8;
    *(bf16x8*)(dhi + off) = vh;
    *(bf16x8*)(dlo + off) = vl;
}

// ---------------------------------------------------------------------------
// Fragment-direct hi/lo bf16 MFMA GEMM.
// D[m,n] = sum_k A[m,k]*B[n,k]  (both operands K-inner, pre-swizzled frags)
// Block: 256 thr = 4 waves in 2x2; block tile 64(m) x 128(n);
// wave tile 32x64 = 2x4 fragments of 16x16, K-step 32 (1 k-frag).
// Split-K via blockIdx.z (ktPerSplit k-frags each), C += z*csliceStride.
// ---------------------------------------------------------------------------
template<bool RELU>
__global__ __launch_bounds__(256)
void gemm_hilo(const short* __restrict__ Ahi, const short* __restrict__ Alo,
               const short* __restrict__ Bhi, const short* __restrict__ Blo,
               const float* __restrict__ bias,   // per-m, only when RELU
               float* __restrict__ C,
               int KT, int ktPerSplit, size_t csliceStride, int ldc)
{
    const int lane = threadIdx.x & 63;
    const int wid  = threadIdx.x >> 6;
    const int wm = wid & 1, wn = wid >> 1;
    const int mt0 = blockIdx.x * 4 + wm * 2;
    const int nt0 = blockIdx.y * 8 + wn * 4;
    const int ktBeg = blockIdx.z * ktPerSplit;
    const int ktEnd = ktBeg + ktPerSplit;
    C += (size_t)blockIdx.z * csliceStride;

    f32x4 acc[2][4] = {};
    const size_t laneOff = (size_t)lane * 8;

    #pragma unroll 2
    for (int kt = ktBeg; kt < ktEnd; ++kt) {
        bf16x8 ah[2], al[2], bh[4], bl[4];
        #pragma unroll
        for (int i = 0; i < 2; ++i) {
            const size_t off = ((size_t)(mt0 + i) * KT + kt) * 512 + laneOff;
            ah[i] = *(const bf16x8*)(Ahi + off);
            al[i] = *(const bf16x8*)(Alo + off);
        }
        #pragma unroll
        for (int j = 0; j < 4; ++j) {
            const size_t off = ((size_t)(nt0 + j) * KT + kt) * 512 + laneOff;
            bh[j] = *(const bf16x8*)(Bhi + off);
            bl[j] = *(const bf16x8*)(Blo + off);
        }
        #pragma unroll
        for (int i = 0; i < 2; ++i)
            #pragma unroll
            for (int j = 0; j < 4; ++j) {
                acc[i][j] = __builtin_amdgcn_mfma_f32_16x16x32_bf16(ah[i], bh[j], acc[i][j], 0, 0, 0);
                acc[i][j] = __builtin_amdgcn_mfma_f32_16x16x32_bf16(ah[i], bl[j], acc[i][j], 0, 0, 0);
                acc[i][j] = __builtin_amdgcn_mfma_f32_16x16x32_bf16(al[i], bh[j], acc[i][j], 0, 0, 0);
            }
    }

    // C/D layout: col = lane&15, row = (lane>>4)*4 + r   [measured m89/m91]
    const int col = lane & 15;
    const int rb  = (lane >> 4) * 4;
    #pragma unroll
    for (int i = 0; i < 2; ++i) {
        #pragma unroll
        for (int r = 0; r < 4; ++r) {
            const int m = (mt0 + i) * 16 + rb + r;
            float bv = 0.f;
            if (RELU) bv = bias[m];
            #pragma unroll
            for (int j = 0; j < 4; ++j) {
                const int n = (nt0 + j) * 16 + col;
                float v = acc[i][j][r] + bv;
                if (RELU) v = fmaxf(v, 0.f);
                C[(size_t)m * ldc + n] = v;
            }
        }
    }
}

// ---------------------------------------------------------------------------
// Condensed layer: out[o,b] = relu( sum_f W[o,f] * h[idx[o,f], b] + bm[o] )
// h, out: (N_MID, B_SZ) row-major. One block per o, 256 threads, float2 over b.
// ---------------------------------------------------------------------------
__global__ __launch_bounds__(256)
void condensed_relu(const float* __restrict__ h,
                    const int*   __restrict__ idx,
                    const float* __restrict__ W,
                    const float* __restrict__ bm,
                    float* __restrict__ out)
{
    __shared__ int   sIdx[FANIN];
    __shared__ float sW[FANIN];

    const int o = blockIdx.x;
    const int t = threadIdx.x;

    if (t < FANIN) {
        sIdx[t] = idx[(size_t)o * FANIN + t];
        sW[t]   = W[(size_t)o * FANIN + t];
    }
    __syncthreads();

    float2 acc = {0.f, 0.f};
    #pragma unroll 8
    for (int f = 0; f < FANIN; ++f) {
        const int   j = sIdx[f];
        const float w = sW[f];
        const float2 hv = *(const float2*)&h[(size_t)j * B_SZ + 2 * t];
        acc.x += w * hv.x;
        acc.y += w * hv.y;
    }
    const float bb = bm[o];
    acc.x = fmaxf(acc.x + bb, 0.f);
    acc.y = fmaxf(acc.y + bb, 0.f);
    *(float2*)&out[(size_t)o * B_SZ + 2 * t] = acc;
}

// ---------------------------------------------------------------------------
// Reduce split-K partials + bias: y[b,n] = sum_s P[s,b,n] + b_out[n]
// P has padded col stride N_OUTP.
// ---------------------------------------------------------------------------
__global__ __launch_bounds__(256)
void reduce_out(const float* __restrict__ P,
                const float* __restrict__ b_out,
                float* __restrict__ y)
{
    const int i = blockIdx.x * 256 + threadIdx.x;
    if (i >= (B_SZ * N_OUT) / 4) return;
    const int e = i * 4;
    const int b = e / N_OUT;
    const int n = e - b * N_OUT;                  // multiple of 4

    float4 acc = *(const float4*)&b_out[n];
    #pragma unroll
    for (int s = 0; s < SPLITK; ++s) {
        const float4 p = *(const float4*)&P[((size_t)s * B_SZ + b) * N_OUTP + n];
        acc.x += p.x; acc.y += p.y; acc.z += p.z; acc.w += p.w;
    }
    *(float4*)&y[e] = acc;
}

// ---------------------------------------------------------------------------
extern "C" void kernel_launch(void* const* d_in, const int* in_sizes, int n_in,
                              void* d_out, int out_size, void* d_ws, size_t ws_size,
                              hipStream_t stream)
{
    const float* x      = (const float*)d_in[0];  // (512, 1024)
    const float* W_in   = (const float*)d_in[1];  // (8192, 1024)
    const float* b_in   = (const float*)d_in[2];  // (8192)
    const float* W_mid  = (const float*)d_in[3];  // (2, 8192, 64)
    const float* b_mid  = (const float*)d_in[4];  // (2, 8192)
    const float* W_out  = (const float*)d_in[5];  // (1000, 8192)
    const float* b_out  = (const float*)d_in[6];  // (1000)
    const int*   indx   = (const int*)d_in[7];    // (8192, 64)

    float* y = (float*)d_out;                     // (512, 1000)

    // ---- workspace layout (bytes) ----
    char* w = (char*)d_ws;
    float* h0   = (float*)w;                 w += (size_t)N_MID * B_SZ * 4;      // 16.78 MB
    float* h1   = (float*)w;                 w += (size_t)N_MID * B_SZ * 4;      // 16.78 MB
    float* P    = (float*)w;                 w += (size_t)SPLITK * B_SZ * N_OUTP * 4; // 16.78 MB
    short* Whi  = (short*)w;                 w += (size_t)N_MID * N_IN * 2;      // 16.78 MB (W_in; reused for W_out)
    short* Wlo  = (short*)w;                 w += (size_t)N_MID * N_IN * 2;      // 16.78 MB
    short* xhi  = (short*)w;                 w += (size_t)B_SZ * N_IN * 2;       // 1.05 MB
    short* xlo  = (short*)w;                 w += (size_t)B_SZ * N_IN * 2;       // 1.05 MB
    short* hthi = (short*)w;                 w += (size_t)B_SZ * N_MID * 2;      // 8.39 MB
    short* htlo = (short*)w;                 w += (size_t)B_SZ * N_MID * 2;      // 8.39 MB
    // total ~102.8 MB

    const int KT1 = N_IN / 32;    // 32 k-frags (GEMM1)
    const int KT3 = N_MID / 32;   // 256 k-frags (GEMM3)

    // 1) conversions for GEMM1
    {
        const int nf = (N_MID / 16) * KT1;   // 16384
        conv_nt<<<nf / 4, 256, 0, stream>>>(W_in, N_MID, N_IN, KT1, Whi, Wlo, nf);
    }
    {
        const int nf = (B_SZ / 16) * KT1;    // 1024
        conv_nt<<<nf / 4, 256, 0, stream>>>(x, B_SZ, N_IN, KT1, xhi, xlo, nf);
    }

    // 2) GEMM1: h0[m, b] = relu(W_in x^T + b_in), m-frags 512 -> grid.x 128
    {
        dim3 g(N_MID / 64, B_SZ / 128, 1);
        gemm_hilo<true><<<g, 256, 0, stream>>>(Whi, Wlo, xhi, xlo, b_in, h0,
                                               KT1, KT1, 0, B_SZ);
    }

    // 3) condensed layers (fp32)
    condensed_relu<<<N_MID, 256, 0, stream>>>(h0, indx, W_mid, b_mid, h1);
    condensed_relu<<<N_MID, 256, 0, stream>>>(h1, indx,
                                              W_mid + (size_t)N_MID * FANIN,
                                              b_mid + N_MID, h0);

    // 4) conversions for GEMM3: h^T (transpose) and W_out (padded rows)
    {
        const int nf = (B_SZ / 16) * KT3;    // 8192
        conv_t<<<nf / 4, 256, 0, stream>>>(h0, B_SZ, KT3, hthi, htlo, nf);
    }
    {
        const int nf = (N_OUTP / 16) * KT3;  // 16384
        conv_nt<<<nf / 4, 256, 0, stream>>>(W_out, N_OUT, N_MID, KT3, Whi, Wlo, nf);
    }

    // 5) GEMM3 split-K: P[s, b, n] = partial sums (A = h^T frags, B = W_out frags)
    {
        dim3 g(B_SZ / 64, N_OUTP / 128, SPLITK);
        gemm_hilo<false><<<g, 256, 0, stream>>>(hthi, htlo, Whi, Wlo, nullptr, P,
                                                KT3, KT3 / SPLITK,
                                                (size_t)B_SZ * N_OUTP, N_OUTP);
    }

    // 6) reduce + bias
    reduce_out<<<(B_SZ * N_OUT / 4 + 255) / 256, 256, 0, stream>>>(P, b_out, y);
}

// Round 4
// 363.440 us; speedup vs baseline: 1.6211x; 1.2458x over previous
//
#include <hip/hip_runtime.h>

#define B_SZ   512
#define N_IN   1024
#define N_MID  8192
#define N_OUT  1000
#define N_OUTP 1024          // padded
#define FANIN  64
#define SPLITK 8
#define NCHUNK 4
#define BCH    (B_SZ / NCHUNK)   // 128 -> 4 MB fp32 slice == one XCD L2

typedef __attribute__((ext_vector_type(8))) short bf16x8;
typedef __attribute__((ext_vector_type(4))) float f32x4;

static __device__ __forceinline__ unsigned short f2bf(float f) {
    unsigned u = __float_as_uint(f);
    unsigned r = u + 0x7FFF + ((u >> 16) & 1);   // round-to-nearest-even
    return (unsigned short)(r >> 16);
}
static __device__ __forceinline__ float bf2f(unsigned short h) {
    return __uint_as_float(((unsigned)h) << 16);
}

// ---------------------------------------------------------------------------
// Convert fp32 (R x K, row-major, K-inner) -> hi/lo bf16 in MFMA fragment
// order. Fragment (mt,kt) covers rows mt*16..+15, k kt*32..+31.
// Slot: lane l holds (m = mt*16 + (l&15), k = kt*32 + (l>>4)*8 + j), j=0..7.
// Buffer: frag fid = mt*KT + kt at dhi[fid*512 + lane*8 + j].
// Rows >= R are zero-padded.
// ---------------------------------------------------------------------------
__global__ __launch_bounds__(256)
void conv_nt(const float* __restrict__ src, int R, int K, int KT,
             short* __restrict__ dhi, short* __restrict__ dlo, int nfrag)
{
    const int wid = threadIdx.x >> 6, lane = threadIdx.x & 63;
    const int fid = blockIdx.x * 4 + wid;
    if (fid >= nfrag) return;
    const int mt = fid / KT, kt = fid - mt * KT;
    const int m = mt * 16 + (lane & 15);
    const int k = kt * 32 + (lane >> 4) * 8;

    float v[8];
    if (m < R) {
        const float4 a = *(const float4*)(src + (size_t)m * K + k);
        const float4 b = *(const float4*)(src + (size_t)m * K + k + 4);
        v[0]=a.x; v[1]=a.y; v[2]=a.z; v[3]=a.w;
        v[4]=b.x; v[5]=b.y; v[6]=b.z; v[7]=b.w;
    } else {
        #pragma unroll
        for (int j = 0; j < 8; ++j) v[j] = 0.f;
    }
    bf16x8 vh, vl;
    #pragma unroll
    for (int j = 0; j < 8; ++j) {
        const unsigned short h = f2bf(v[j]);
        vh[j] = (short)h;
        vl[j] = (short)f2bf(v[j] - bf2f(h));
    }
    const size_t off = (size_t)fid * 512 + lane * 8;
    *(bf16x8*)(dhi + off) = vh;
    *(bf16x8*)(dlo + off) = vl;
}

// ---------------------------------------------------------------------------
// Transposing variant: src is (K x Bcols) fp32 (k-major); produce fragments of
// src^T (Bcols x K). Frag (bt,kt): lane holds (b = bt*16+(l&15),
// k = kt*32+(l>>4)*8+j).
// ---------------------------------------------------------------------------
__global__ __launch_bounds__(256)
void conv_t(const float* __restrict__ src, int Bc, int KT,
            short* __restrict__ dhi, short* __restrict__ dlo, int nfrag)
{
    const int wid = threadIdx.x >> 6, lane = threadIdx.x & 63;
    const int fid = blockIdx.x * 4 + wid;
    if (fid >= nfrag) return;
    const int bt = fid / KT, kt = fid - bt * KT;
    const int b = bt * 16 + (lane & 15);
    const int k = kt * 32 + (lane >> 4) * 8;

    bf16x8 vh, vl;
    #pragma unroll
    for (int j = 0; j < 8; ++j) {
        const float v = src[(size_t)(k + j) * Bc + b];
        const unsigned short h = f2bf(v);
        vh[j] = (short)h;
        vl[j] = (short)f2bf(v - bf2f(h));
    }
    const size_t off = (size_t)fid * 512 + lane * 8;
    *(bf16x8*)(dhi + off) = vh;
    *(bf16x8*)(dlo + off) = vl;
}

// ---------------------------------------------------------------------------
// Fragment-direct hi/lo bf16 MFMA GEMM.
// D[m,n] = sum_k A[m,k]*B[n,k]  (both operands K-inner, pre-swizzled frags)
// Block: 256 thr = 4 waves in 2x2; block tile 64(m) x 128(n);
// wave tile 32x64 = 2x4 fragments of 16x16, K-step 32 (1 k-frag).
// Split-K via blockIdx.z (ktPerSplit k-frags each), C += z*csliceStride.
// ---------------------------------------------------------------------------
template<bool RELU>
__global__ __launch_bounds__(256)
void gemm_hilo(const short* __restrict__ Ahi, const short* __restrict__ Alo,
               const short* __restrict__ Bhi, const short* __restrict__ Blo,
               const float* __restrict__ bias,   // per-m, only when RELU
               float* __restrict__ C,
               int KT, int ktPerSplit, size_t csliceStride, int ldc)
{
    const int lane = threadIdx.x & 63;
    const int wid  = threadIdx.x >> 6;
    const int wm = wid & 1, wn = wid >> 1;
    const int mt0 = blockIdx.x * 4 + wm * 2;
    const int nt0 = blockIdx.y * 8 + wn * 4;
    const int ktBeg = blockIdx.z * ktPerSplit;
    const int ktEnd = ktBeg + ktPerSplit;
    C += (size_t)blockIdx.z * csliceStride;

    f32x4 acc[2][4] = {};
    const size_t laneOff = (size_t)lane * 8;

    #pragma unroll 2
    for (int kt = ktBeg; kt < ktEnd; ++kt) {
        bf16x8 ah[2], al[2], bh[4], bl[4];
        #pragma unroll
        for (int i = 0; i < 2; ++i) {
            const size_t off = ((size_t)(mt0 + i) * KT + kt) * 512 + laneOff;
            ah[i] = *(const bf16x8*)(Ahi + off);
            al[i] = *(const bf16x8*)(Alo + off);
        }
        #pragma unroll
        for (int j = 0; j < 4; ++j) {
            const size_t off = ((size_t)(nt0 + j) * KT + kt) * 512 + laneOff;
            bh[j] = *(const bf16x8*)(Bhi + off);
            bl[j] = *(const bf16x8*)(Blo + off);
        }
        #pragma unroll
        for (int i = 0; i < 2; ++i)
            #pragma unroll
            for (int j = 0; j < 4; ++j) {
                acc[i][j] = __builtin_amdgcn_mfma_f32_16x16x32_bf16(ah[i], bh[j], acc[i][j], 0, 0, 0);
                acc[i][j] = __builtin_amdgcn_mfma_f32_16x16x32_bf16(ah[i], bl[j], acc[i][j], 0, 0, 0);
                acc[i][j] = __builtin_amdgcn_mfma_f32_16x16x32_bf16(al[i], bh[j], acc[i][j], 0, 0, 0);
            }
    }

    // C/D layout: col = lane&15, row = (lane>>4)*4 + r   [measured m89/m91]
    const int col = lane & 15;
    const int rb  = (lane >> 4) * 4;
    #pragma unroll
    for (int i = 0; i < 2; ++i) {
        #pragma unroll
        for (int r = 0; r < 4; ++r) {
            const int m = (mt0 + i) * 16 + rb + r;
            float bv = 0.f;
            if (RELU) bv = bias[m];
            #pragma unroll
            for (int j = 0; j < 4; ++j) {
                const int n = (nt0 + j) * 16 + col;
                float v = acc[i][j][r] + bv;
                if (RELU) v = fmaxf(v, 0.f);
                C[(size_t)m * ldc + n] = v;
            }
        }
    }
}

// ---------------------------------------------------------------------------
// Condensed layer, B-chunked for L2 residency:
// out[o, c*BCH + bb] = relu( sum_f W[o,f] * h[idx[o,f], c*BCH + bb] + bm[o] )
// Chunk-major block order: blocks [c*2048, (c+1)*2048) all work on chunk c,
// whose h-slice (8192 x 128 fp32 = 4 MB) fits a single XCD L2. 4 o's per
// block, one wave each; per-wave LDS staging of idx/W rows.
// ---------------------------------------------------------------------------
__global__ __launch_bounds__(256)
void condensed_relu_chunked(const float* __restrict__ h,
                            const int*   __restrict__ idx,
                            const float* __restrict__ W,
                            const float* __restrict__ bm,
                            float* __restrict__ out)
{
    __shared__ int   sIdx[4][FANIN];
    __shared__ float sW[4][FANIN];

    const int w     = threadIdx.x >> 6;
    const int lane  = threadIdx.x & 63;
    const int chunk = blockIdx.x >> 11;                 // 2048 blocks/chunk
    const int o     = ((blockIdx.x & 2047) << 2) + w;
    const int bOff  = chunk * BCH + lane * 2;

    sIdx[w][lane] = idx[(size_t)o * FANIN + lane];
    sW[w][lane]   = W[(size_t)o * FANIN + lane];
    __syncthreads();

    float2 acc = {0.f, 0.f};
    #pragma unroll 8
    for (int f = 0; f < FANIN; ++f) {
        const int   j  = sIdx[w][f];
        const float wv = sW[w][f];
        const float2 hv = *(const float2*)&h[(size_t)j * B_SZ + bOff];
        acc.x += wv * hv.x;
        acc.y += wv * hv.y;
    }
    const float bb = bm[o];
    acc.x = fmaxf(acc.x + bb, 0.f);
    acc.y = fmaxf(acc.y + bb, 0.f);
    *(float2*)&out[(size_t)o * B_SZ + bOff] = acc;
}

// ---------------------------------------------------------------------------
// Reduce split-K partials + bias: y[b,n] = sum_s P[s,b,n] + b_out[n]
// P has padded col stride N_OUTP.
// ---------------------------------------------------------------------------
__global__ __launch_bounds__(256)
void reduce_out(const float* __restrict__ P,
                const float* __restrict__ b_out,
                float* __restrict__ y)
{
    const int i = blockIdx.x * 256 + threadIdx.x;
    if (i >= (B_SZ * N_OUT) / 4) return;
    const int e = i * 4;
    const int b = e / N_OUT;
    const int n = e - b * N_OUT;                  // multiple of 4

    float4 acc = *(const float4*)&b_out[n];
    #pragma unroll
    for (int s = 0; s < SPLITK; ++s) {
        const float4 p = *(const float4*)&P[((size_t)s * B_SZ + b) * N_OUTP + n];
        acc.x += p.x; acc.y += p.y; acc.z += p.z; acc.w += p.w;
    }
    *(float4*)&y[e] = acc;
}

// ---------------------------------------------------------------------------
extern "C" void kernel_launch(void* const* d_in, const int* in_sizes, int n_in,
                              void* d_out, int out_size, void* d_ws, size_t ws_size,
                              hipStream_t stream)
{
    const float* x      = (const float*)d_in[0];  // (512, 1024)
    const float* W_in   = (const float*)d_in[1];  // (8192, 1024)
    const float* b_in   = (const float*)d_in[2];  // (8192)
    const float* W_mid  = (const float*)d_in[3];  // (2, 8192, 64)
    const float* b_mid  = (const float*)d_in[4];  // (2, 8192)
    const float* W_out  = (const float*)d_in[5];  // (1000, 8192)
    const float* b_out  = (const float*)d_in[6];  // (1000)
    const int*   indx   = (const int*)d_in[7];    // (8192, 64)

    float* y = (float*)d_out;                     // (512, 1000)

    // ---- workspace layout (bytes) ----
    char* w = (char*)d_ws;
    float* h0   = (float*)w;                 w += (size_t)N_MID * B_SZ * 4;      // 16.78 MB
    float* h1   = (float*)w;                 w += (size_t)N_MID * B_SZ * 4;      // 16.78 MB
    float* P    = (float*)w;                 w += (size_t)SPLITK * B_SZ * N_OUTP * 4; // 16.78 MB
    short* Whi  = (short*)w;                 w += (size_t)N_MID * N_IN * 2;      // 16.78 MB (W_in; reused for W_out)
    short* Wlo  = (short*)w;                 w += (size_t)N_MID * N_IN * 2;      // 16.78 MB
    short* xhi  = (short*)w;                 w += (size_t)B_SZ * N_IN * 2;       // 1.05 MB
    short* xlo  = (short*)w;                 w += (size_t)B_SZ * N_IN * 2;       // 1.05 MB
    short* hthi = (short*)w;                 w += (size_t)B_SZ * N_MID * 2;      // 8.39 MB
    short* htlo = (short*)w;                 w += (size_t)B_SZ * N_MID * 2;      // 8.39 MB
    // total ~102.8 MB

    const int KT1 = N_IN / 32;    // 32 k-frags (GEMM1)
    const int KT3 = N_MID / 32;   // 256 k-frags (GEMM3)

    // 1) conversions for GEMM1
    {
        const int nf = (N_MID / 16) * KT1;   // 16384
        conv_nt<<<nf / 4, 256, 0, stream>>>(W_in, N_MID, N_IN, KT1, Whi, Wlo, nf);
    }
    {
        const int nf = (B_SZ / 16) * KT1;    // 1024
        conv_nt<<<nf / 4, 256, 0, stream>>>(x, B_SZ, N_IN, KT1, xhi, xlo, nf);
    }

    // 2) GEMM1: h0[m, b] = relu(W_in x^T + b_in)
    {
        dim3 g(N_MID / 64, B_SZ / 128, 1);
        gemm_hilo<true><<<g, 256, 0, stream>>>(Whi, Wlo, xhi, xlo, b_in, h0,
                                               KT1, KT1, 0, B_SZ);
    }

    // 3) condensed layers (fp32, B-chunked for L2 residency)
    condensed_relu_chunked<<<NCHUNK * 2048, 256, 0, stream>>>(h0, indx, W_mid, b_mid, h1);
    condensed_relu_chunked<<<NCHUNK * 2048, 256, 0, stream>>>(h1, indx,
                                              W_mid + (size_t)N_MID * FANIN,
                                              b_mid + N_MID, h0);

    // 4) conversions for GEMM3: h^T (transpose) and W_out (padded rows)
    {
        const int nf = (B_SZ / 16) * KT3;    // 8192
        conv_t<<<nf / 4, 256, 0, stream>>>(h0, B_SZ, KT3, hthi, htlo, nf);
    }
    {
        const int nf = (N_OUTP / 16) * KT3;  // 16384
        conv_nt<<<nf / 4, 256, 0, stream>>>(W_out, N_OUT, N_MID, KT3, Whi, Wlo, nf);
    }

    // 5) GEMM3 split-K: P[s, b, n] = partial sums (A = h^T frags, B = W_out frags)
    {
        dim3 g(B_SZ / 64, N_OUTP / 128, SPLITK);
        gemm_hilo<false><<<g, 256, 0, stream>>>(hthi, htlo, Whi, Wlo, nullptr, P,
                                                KT3, KT3 / SPLITK,
                                                (size_t)B_SZ * N_OUTP, N_OUTP);
    }

    // 6) reduce + bias
    reduce_out<<<(B_SZ * N_OUT / 4 + 255) / 256, 256, 0, stream>>>(P, b_out, y);
}

// Round 6
// 302.345 us; speedup vs baseline: 1.9487x; 1.2021x over previous
//
#include <hip/hip_runtime.h>

#define B_SZ   512
#define N_IN   1024
#define N_MID  8192
#define N_OUT  1000
#define N_OUTP 1024          // padded
#define FANIN  64
#define SPLITK 8
#define NCHUNK 2
#define BCH    (B_SZ / NCHUNK)   // 256 cols -> 8192*256*2B = 4 MB bf16 slice == one XCD L2

typedef __attribute__((ext_vector_type(8))) short bf16x8;
typedef __attribute__((ext_vector_type(4))) short bf16x4;
typedef __attribute__((ext_vector_type(4))) float f32x4;

static __device__ __forceinline__ unsigned short f2bf(float f) {
    unsigned u = __float_as_uint(f);
    unsigned r = u + 0x7FFF + ((u >> 16) & 1);   // round-to-nearest-even
    return (unsigned short)(r >> 16);
}
static __device__ __forceinline__ float bf2f(unsigned short h) {
    return __uint_as_float(((unsigned)h) << 16);
}

// ---------------------------------------------------------------------------
// Convert fp32 (R x K, row-major, K-inner) -> hi/lo bf16 in MFMA fragment
// order. Fragment (mt,kt) covers rows mt*16..+15, k kt*32..+31.
// Slot: lane l holds (m = mt*16 + (l&15), k = kt*32 + (l>>4)*8 + j), j=0..7.
// Rows >= R are zero-padded.
// ---------------------------------------------------------------------------
__global__ __launch_bounds__(256)
void conv_nt(const float* __restrict__ src, int R, int K, int KT,
             short* __restrict__ dhi, short* __restrict__ dlo, int nfrag)
{
    const int wid = threadIdx.x >> 6, lane = threadIdx.x & 63;
    const int fid = blockIdx.x * 4 + wid;
    if (fid >= nfrag) return;
    const int mt = fid / KT, kt = fid - mt * KT;
    const int m = mt * 16 + (lane & 15);
    const int k = kt * 32 + (lane >> 4) * 8;

    float v[8];
    if (m < R) {
        const float4 a = *(const float4*)(src + (size_t)m * K + k);
        const float4 b = *(const float4*)(src + (size_t)m * K + k + 4);
        v[0]=a.x; v[1]=a.y; v[2]=a.z; v[3]=a.w;
        v[4]=b.x; v[5]=b.y; v[6]=b.z; v[7]=b.w;
    } else {
        #pragma unroll
        for (int j = 0; j < 8; ++j) v[j] = 0.f;
    }
    bf16x8 vh, vl;
    #pragma unroll
    for (int j = 0; j < 8; ++j) {
        const unsigned short h = f2bf(v[j]);
        vh[j] = (short)h;
        vl[j] = (short)f2bf(v[j] - bf2f(h));
    }
    const size_t off = (size_t)fid * 512 + lane * 8;
    *(bf16x8*)(dhi + off) = vh;
    *(bf16x8*)(dlo + off) = vl;
}

// ---------------------------------------------------------------------------
// Transposing variant: src is (K x Bcols) fp32 (k-major); produce fragments of
// src^T (Bcols x K). Frag (bt,kt): lane holds (b = bt*16+(l&15),
// k = kt*32+(l>>4)*8+j).
// ---------------------------------------------------------------------------
__global__ __launch_bounds__(256)
void conv_t(const float* __restrict__ src, int Bc, int KT,
            short* __restrict__ dhi, short* __restrict__ dlo, int nfrag)
{
    const int wid = threadIdx.x >> 6, lane = threadIdx.x & 63;
    const int fid = blockIdx.x * 4 + wid;
    if (fid >= nfrag) return;
    const int bt = fid / KT, kt = fid - bt * KT;
    const int b = bt * 16 + (lane & 15);
    const int k = kt * 32 + (lane >> 4) * 8;

    bf16x8 vh, vl;
    #pragma unroll
    for (int j = 0; j < 8; ++j) {
        const float v = src[(size_t)(k + j) * Bc + b];
        const unsigned short h = f2bf(v);
        vh[j] = (short)h;
        vl[j] = (short)f2bf(v - bf2f(h));
    }
    const size_t off = (size_t)fid * 512 + lane * 8;
    *(bf16x8*)(dhi + off) = vh;
    *(bf16x8*)(dlo + off) = vl;
}

// ---------------------------------------------------------------------------
// Fragment-direct hi/lo bf16 MFMA GEMM.
// D[m,n] = sum_k A[m,k]*B[n,k]  (both operands K-inner, pre-swizzled frags)
// 4 waves 2x2; block tile 64(m) x 128(n); wave tile 32x64; K-step 32.
// OBF16: write output as bf16 (used for the gather-consumed h buffer).
// ---------------------------------------------------------------------------
template<bool RELU, bool OBF16>
__global__ __launch_bounds__(256)
void gemm_hilo(const short* __restrict__ Ahi, const short* __restrict__ Alo,
               const short* __restrict__ Bhi, const short* __restrict__ Blo,
               const float* __restrict__ bias,   // per-m, only when RELU
               void* __restrict__ Cv,
               int KT, int ktPerSplit, size_t csliceStride, int ldc)
{
    const int lane = threadIdx.x & 63;
    const int wid  = threadIdx.x >> 6;
    const int wm = wid & 1, wn = wid >> 1;
    const int mt0 = blockIdx.x * 4 + wm * 2;
    const int nt0 = blockIdx.y * 8 + wn * 4;
    const int ktBeg = blockIdx.z * ktPerSplit;
    const int ktEnd = ktBeg + ktPerSplit;
    const size_t cbase = (size_t)blockIdx.z * csliceStride;

    f32x4 acc[2][4] = {};
    const size_t laneOff = (size_t)lane * 8;

    #pragma unroll 2
    for (int kt = ktBeg; kt < ktEnd; ++kt) {
        bf16x8 ah[2], al[2], bh[4], bl[4];
        #pragma unroll
        for (int i = 0; i < 2; ++i) {
            const size_t off = ((size_t)(mt0 + i) * KT + kt) * 512 + laneOff;
            ah[i] = *(const bf16x8*)(Ahi + off);
            al[i] = *(const bf16x8*)(Alo + off);
        }
        #pragma unroll
        for (int j = 0; j < 4; ++j) {
            const size_t off = ((size_t)(nt0 + j) * KT + kt) * 512 + laneOff;
            bh[j] = *(const bf16x8*)(Bhi + off);
            bl[j] = *(const bf16x8*)(Blo + off);
        }
        #pragma unroll
        for (int i = 0; i < 2; ++i)
            #pragma unroll
            for (int j = 0; j < 4; ++j) {
                acc[i][j] = __builtin_amdgcn_mfma_f32_16x16x32_bf16(ah[i], bh[j], acc[i][j], 0, 0, 0);
                acc[i][j] = __builtin_amdgcn_mfma_f32_16x16x32_bf16(ah[i], bl[j], acc[i][j], 0, 0, 0);
                acc[i][j] = __builtin_amdgcn_mfma_f32_16x16x32_bf16(al[i], bh[j], acc[i][j], 0, 0, 0);
            }
    }

    // C/D layout: col = lane&15, row = (lane>>4)*4 + r   [measured m89/m91]
    const int col = lane & 15;
    const int rb  = (lane >> 4) * 4;
    #pragma unroll
    for (int i = 0; i < 2; ++i) {
        #pragma unroll
        for (int r = 0; r < 4; ++r) {
            const int m = (mt0 + i) * 16 + rb + r;
            float bv = 0.f;
            if (RELU) bv = bias[m];
            #pragma unroll
            for (int j = 0; j < 4; ++j) {
                const int n = (nt0 + j) * 16 + col;
                float v = acc[i][j][r] + bv;
                if (RELU) v = fmaxf(v, 0.f);
                if (OBF16)
                    ((unsigned short*)Cv)[cbase + (size_t)m * ldc + n] = f2bf(v);
                else
                    ((float*)Cv)[cbase + (size_t)m * ldc + n] = v;
            }
        }
    }
}

// ---------------------------------------------------------------------------
// Condensed layer, bf16 gather, B-chunked for L2 residency:
// out[o, b] = relu( sum_f W[o,f] * h[idx[o,f], b] + bm[o] )
// h: (N_MID, B_SZ) bf16. Chunk = 256 cols -> 4 MB slice per XCD L2.
// Chunk-major block order (2048 blocks/chunk). 4 o's per block (1 wave each),
// per-wave LDS idx/W staging; each lane: 4 cols via 8 B bf16x4 loads.
// ---------------------------------------------------------------------------
template<bool OUT_BF16>
__global__ __launch_bounds__(256)
void condensed_relu_g(const unsigned short* __restrict__ h,
                      const int*   __restrict__ idx,
                      const float* __restrict__ W,
                      const float* __restrict__ bm,
                      void* __restrict__ outv)
{
    __shared__ int   sIdx[4][FANIN];
    __shared__ float sW[4][FANIN];

    const int w     = threadIdx.x >> 6;
    const int lane  = threadIdx.x & 63;
    const int chunk = blockIdx.x >> 11;                 // 2048 blocks/chunk
    const int o     = ((blockIdx.x & 2047) << 2) + w;
    const int bOff  = chunk * BCH + lane * 4;

    sIdx[w][lane] = idx[(size_t)o * FANIN + lane];
    sW[w][lane]   = W[(size_t)o * FANIN + lane];
    __syncthreads();

    float a0 = 0.f, a1 = 0.f, a2 = 0.f, a3 = 0.f;
    #pragma unroll 8
    for (int f = 0; f < FANIN; ++f) {
        const int   j  = sIdx[w][f];
        const float wv = sW[w][f];
        const bf16x4 hv = *(const bf16x4*)&h[(size_t)j * B_SZ + bOff];
        a0 += wv * bf2f((unsigned short)hv[0]);
        a1 += wv * bf2f((unsigned short)hv[1]);
        a2 += wv * bf2f((unsigned short)hv[2]);
        a3 += wv * bf2f((unsigned short)hv[3]);
    }
    const float bb = bm[o];
    a0 = fmaxf(a0 + bb, 0.f);
    a1 = fmaxf(a1 + bb, 0.f);
    a2 = fmaxf(a2 + bb, 0.f);
    a3 = fmaxf(a3 + bb, 0.f);

    if (OUT_BF16) {
        bf16x4 ov;
        ov[0] = (short)f2bf(a0); ov[1] = (short)f2bf(a1);
        ov[2] = (short)f2bf(a2); ov[3] = (short)f2bf(a3);
        *(bf16x4*)&((unsigned short*)outv)[(size_t)o * B_SZ + bOff] = ov;
    } else {
        float4 ov; ov.x = a0; ov.y = a1; ov.z = a2; ov.w = a3;
        *(float4*)&((float*)outv)[(size_t)o * B_SZ + bOff] = ov;
    }
}

// ---------------------------------------------------------------------------
// Reduce split-K partials + bias: y[b,n] = sum_s P[s,b,n] + b_out[n]
// P has padded col stride N_OUTP.
// ---------------------------------------------------------------------------
__global__ __launch_bounds__(256)
void reduce_out(const float* __restrict__ P,
                const float* __restrict__ b_out,
                float* __restrict__ y)
{
    const int i = blockIdx.x * 256 + threadIdx.x;
    if (i >= (B_SZ * N_OUT) / 4) return;
    const int e = i * 4;
    const int b = e / N_OUT;
    const int n = e - b * N_OUT;                  // multiple of 4

    float4 acc = *(const float4*)&b_out[n];
    #pragma unroll
    for (int s = 0; s < SPLITK; ++s) {
        const float4 p = *(const float4*)&P[((size_t)s * B_SZ + b) * N_OUTP + n];
        acc.x += p.x; acc.y += p.y; acc.z += p.z; acc.w += p.w;
    }
    *(float4*)&y[e] = acc;
}

// ---------------------------------------------------------------------------
extern "C" void kernel_launch(void* const* d_in, const int* in_sizes, int n_in,
                              void* d_out, int out_size, void* d_ws, size_t ws_size,
                              hipStream_t stream)
{
    const float* x      = (const float*)d_in[0];  // (512, 1024)
    const float* W_in   = (const float*)d_in[1];  // (8192, 1024)
    const float* b_in   = (const float*)d_in[2];  // (8192)
    const float* W_mid  = (const float*)d_in[3];  // (2, 8192, 64)
    const float* b_mid  = (const float*)d_in[4];  // (2, 8192)
    const float* W_out  = (const float*)d_in[5];  // (1000, 8192)
    const float* b_out  = (const float*)d_in[6];  // (1000)
    const int*   indx   = (const int*)d_in[7];    // (8192, 64)

    float* y = (float*)d_out;                     // (512, 1000)

    // ---- workspace layout ----
    char* w = (char*)d_ws;
    unsigned short* hA = (unsigned short*)w; w += (size_t)N_MID * B_SZ * 2;  // 8.4 MB (bf16)
    unsigned short* hB = (unsigned short*)w; w += (size_t)N_MID * B_SZ * 2;  // 8.4 MB (bf16)
    float* hC   = (float*)w;                 w += (size_t)N_MID * B_SZ * 4;  // 16.8 MB (fp32)
    float* P    = (float*)w;                 w += (size_t)SPLITK * B_SZ * N_OUTP * 4; // 16.8 MB
    short* Whi  = (short*)w;                 w += (size_t)N_MID * N_IN * 2;  // 16.8 MB (W_in; reused for W_out)
    short* Wlo  = (short*)w;                 w += (size_t)N_MID * N_IN * 2;  // 16.8 MB
    short* xhi  = (short*)w;                 w += (size_t)B_SZ * N_IN * 2;   // 1.05 MB
    short* xlo  = (short*)w;                 w += (size_t)B_SZ * N_IN * 2;   // 1.05 MB
    short* hthi = (short*)w;                 w += (size_t)B_SZ * N_MID * 2;  // 8.4 MB
    short* htlo = (short*)w;                 w += (size_t)B_SZ * N_MID * 2;  // 8.4 MB
    // total ~94.5 MB

    const int KT1 = N_IN / 32;    // 32 k-frags (GEMM1)
    const int KT3 = N_MID / 32;   // 256 k-frags (GEMM3)

    // 1) conversions for GEMM1
    {
        const int nf = (N_MID / 16) * KT1;   // 16384
        conv_nt<<<nf / 4, 256, 0, stream>>>(W_in, N_MID, N_IN, KT1, Whi, Wlo, nf);
    }
    {
        const int nf = (B_SZ / 16) * KT1;    // 1024
        conv_nt<<<nf / 4, 256, 0, stream>>>(x, B_SZ, N_IN, KT1, xhi, xlo, nf);
    }

    // 2) GEMM1: hA[m, b] = relu(W_in x^T + b_in)  (bf16 output)
    {
        dim3 g(N_MID / 64, B_SZ / 128, 1);
        gemm_hilo<true, true><<<g, 256, 0, stream>>>(Whi, Wlo, xhi, xlo, b_in, hA,
                                                     KT1, KT1, 0, B_SZ);
    }

    // 3) condensed layers (bf16 gather, chunked for L2 residency)
    condensed_relu_g<true><<<NCHUNK * 2048, 256, 0, stream>>>(hA, indx, W_mid, b_mid, hB);
    condensed_relu_g<false><<<NCHUNK * 2048, 256, 0, stream>>>(hB, indx,
                                              W_mid + (size_t)N_MID * FANIN,
                                              b_mid + N_MID, hC);

    // 4) conversions for GEMM3: hC^T (transpose) and W_out (padded rows)
    {
        const int nf = (B_SZ / 16) * KT3;    // 8192
        conv_t<<<nf / 4, 256, 0, stream>>>(hC, B_SZ, KT3, hthi, htlo, nf);
    }
    {
        const int nf = (N_OUTP / 16) * KT3;  // 16384
        conv_nt<<<nf / 4, 256, 0, stream>>>(W_out, N_OUT, N_MID, KT3, Whi, Wlo, nf);
    }

    // 5) GEMM3 split-K: P[s, b, n] = partial sums (A = hC^T frags, B = W_out frags)
    {
        dim3 g(B_SZ / 64, N_OUTP / 128, SPLITK);
        gemm_hilo<false, false><<<g, 256, 0, stream>>>(hthi, htlo, Whi, Wlo, nullptr, P,
                                                       KT3, KT3 / SPLITK,
                                                       (size_t)B_SZ * N_OUTP, N_OUTP);
    }

    // 6) reduce + bias
    reduce_out<<<(B_SZ * N_OUT / 4 + 255) / 256, 256, 0, stream>>>(P, b_out, y);
}

// Round 7
// 296.026 us; speedup vs baseline: 1.9903x; 1.0213x over previous
//
#include <hip/hip_runtime.h>

#define B_SZ   512
#define N_IN   1024
#define N_MID  8192
#define N_OUT  1000
#define N_OUTP 1024          // padded
#define FANIN  64
#define SPLITK 8
#define NCHUNK 2
#define BCH    (B_SZ / NCHUNK)   // 256 cols -> 8192*256*2B = 4 MB bf16 slice == one XCD L2

typedef __attribute__((ext_vector_type(8))) short bf16x8;
typedef __attribute__((ext_vector_type(4))) short bf16x4;
typedef __attribute__((ext_vector_type(4))) float f32x4;

static __device__ __forceinline__ unsigned short f2bf(float f) {
    unsigned u = __float_as_uint(f);
    unsigned r = u + 0x7FFF + ((u >> 16) & 1);   // round-to-nearest-even
    return (unsigned short)(r >> 16);
}
static __device__ __forceinline__ float bf2f(unsigned short h) {
    return __uint_as_float(((unsigned)h) << 16);
}

// ---------------------------------------------------------------------------
// Convert fp32 (R x K, row-major, K-inner) -> hi/lo bf16 in MFMA fragment
// order. Fragment (mt,kt) covers rows mt*16..+15, k kt*32..+31.
// Slot: lane l holds (m = mt*16 + (l&15), k = kt*32 + (l>>4)*8 + j), j=0..7.
// Rows >= R are zero-padded.
// ---------------------------------------------------------------------------
__global__ __launch_bounds__(256)
void conv_nt(const float* __restrict__ src, int R, int K, int KT,
             short* __restrict__ dhi, short* __restrict__ dlo, int nfrag)
{
    const int wid = threadIdx.x >> 6, lane = threadIdx.x & 63;
    const int fid = blockIdx.x * 4 + wid;
    if (fid >= nfrag) return;
    const int mt = fid / KT, kt = fid - mt * KT;
    const int m = mt * 16 + (lane & 15);
    const int k = kt * 32 + (lane >> 4) * 8;

    float v[8];
    if (m < R) {
        const float4 a = *(const float4*)(src + (size_t)m * K + k);
        const float4 b = *(const float4*)(src + (size_t)m * K + k + 4);
        v[0]=a.x; v[1]=a.y; v[2]=a.z; v[3]=a.w;
        v[4]=b.x; v[5]=b.y; v[6]=b.z; v[7]=b.w;
    } else {
        #pragma unroll
        for (int j = 0; j < 8; ++j) v[j] = 0.f;
    }
    bf16x8 vh, vl;
    #pragma unroll
    for (int j = 0; j < 8; ++j) {
        const unsigned short h = f2bf(v[j]);
        vh[j] = (short)h;
        vl[j] = (short)f2bf(v[j] - bf2f(h));
    }
    const size_t off = (size_t)fid * 512 + lane * 8;
    *(bf16x8*)(dhi + off) = vh;
    *(bf16x8*)(dlo + off) = vl;
}

// ---------------------------------------------------------------------------
// Transposing variant: src is (K x Bcols) fp32 (k-major); produce fragments of
// src^T (Bcols x K). Frag (bt,kt): lane holds (b = bt*16+(l&15),
// k = kt*32+(l>>4)*8+j).
// ---------------------------------------------------------------------------
__global__ __launch_bounds__(256)
void conv_t(const float* __restrict__ src, int Bc, int KT,
            short* __restrict__ dhi, short* __restrict__ dlo, int nfrag)
{
    const int wid = threadIdx.x >> 6, lane = threadIdx.x & 63;
    const int fid = blockIdx.x * 4 + wid;
    if (fid >= nfrag) return;
    const int bt = fid / KT, kt = fid - bt * KT;
    const int b = bt * 16 + (lane & 15);
    const int k = kt * 32 + (lane >> 4) * 8;

    bf16x8 vh, vl;
    #pragma unroll
    for (int j = 0; j < 8; ++j) {
        const float v = src[(size_t)(k + j) * Bc + b];
        const unsigned short h = f2bf(v);
        vh[j] = (short)h;
        vl[j] = (short)f2bf(v - bf2f(h));
    }
    const size_t off = (size_t)fid * 512 + lane * 8;
    *(bf16x8*)(dhi + off) = vh;
    *(bf16x8*)(dlo + off) = vl;
}

// ---------------------------------------------------------------------------
// Fragment-direct hi/lo bf16 MFMA GEMM.
// D[m,n] = sum_k A[m,k]*B[n,k]  (both operands K-inner, pre-swizzled frags)
// Block: 256 thr = 4 waves in 2x2; block tile 64(m) x 64(n);
// wave tile 32x32 = 2x2 fragments of 16x16, K-step 32 (1 k-frag).
// (64x64 doubles the grid vs 64x128 -> 4 waves/SIMD, latency hiding.)
// OBF16: write output as bf16 (used for the gather-consumed h buffer).
// ---------------------------------------------------------------------------
template<bool RELU, bool OBF16>
__global__ __launch_bounds__(256)
void gemm_hilo(const short* __restrict__ Ahi, const short* __restrict__ Alo,
               const short* __restrict__ Bhi, const short* __restrict__ Blo,
               const float* __restrict__ bias,   // per-m, only when RELU
               void* __restrict__ Cv,
               int KT, int ktPerSplit, size_t csliceStride, int ldc)
{
    const int lane = threadIdx.x & 63;
    const int wid  = threadIdx.x >> 6;
    const int wm = wid & 1, wn = wid >> 1;
    const int mt0 = blockIdx.x * 4 + wm * 2;
    const int nt0 = blockIdx.y * 4 + wn * 2;
    const int ktBeg = blockIdx.z * ktPerSplit;
    const int ktEnd = ktBeg + ktPerSplit;
    const size_t cbase = (size_t)blockIdx.z * csliceStride;

    f32x4 acc[2][2] = {};
    const size_t laneOff = (size_t)lane * 8;

    #pragma unroll 2
    for (int kt = ktBeg; kt < ktEnd; ++kt) {
        bf16x8 ah[2], al[2], bh[2], bl[2];
        #pragma unroll
        for (int i = 0; i < 2; ++i) {
            const size_t off = ((size_t)(mt0 + i) * KT + kt) * 512 + laneOff;
            ah[i] = *(const bf16x8*)(Ahi + off);
            al[i] = *(const bf16x8*)(Alo + off);
        }
        #pragma unroll
        for (int j = 0; j < 2; ++j) {
            const size_t off = ((size_t)(nt0 + j) * KT + kt) * 512 + laneOff;
            bh[j] = *(const bf16x8*)(Bhi + off);
            bl[j] = *(const bf16x8*)(Blo + off);
        }
        #pragma unroll
        for (int i = 0; i < 2; ++i)
            #pragma unroll
            for (int j = 0; j < 2; ++j) {
                acc[i][j] = __builtin_amdgcn_mfma_f32_16x16x32_bf16(ah[i], bh[j], acc[i][j], 0, 0, 0);
                acc[i][j] = __builtin_amdgcn_mfma_f32_16x16x32_bf16(ah[i], bl[j], acc[i][j], 0, 0, 0);
                acc[i][j] = __builtin_amdgcn_mfma_f32_16x16x32_bf16(al[i], bh[j], acc[i][j], 0, 0, 0);
            }
    }

    // C/D layout: col = lane&15, row = (lane>>4)*4 + r   [measured m89/m91]
    const int col = lane & 15;
    const int rb  = (lane >> 4) * 4;
    #pragma unroll
    for (int i = 0; i < 2; ++i) {
        #pragma unroll
        for (int r = 0; r < 4; ++r) {
            const int m = (mt0 + i) * 16 + rb + r;
            float bv = 0.f;
            if (RELU) bv = bias[m];
            #pragma unroll
            for (int j = 0; j < 2; ++j) {
                const int n = (nt0 + j) * 16 + col;
                float v = acc[i][j][r] + bv;
                if (RELU) v = fmaxf(v, 0.f);
                if (OBF16)
                    ((unsigned short*)Cv)[cbase + (size_t)m * ldc + n] = f2bf(v);
                else
                    ((float*)Cv)[cbase + (size_t)m * ldc + n] = v;
            }
        }
    }
}

// ---------------------------------------------------------------------------
// Condensed layer, bf16 gather, B-chunked for L2 residency:
// out[o, b] = relu( sum_f W[o,f] * h[idx[o,f], b] + bm[o] )
// h: (N_MID, B_SZ) bf16. Chunk = 256 cols -> 4 MB slice per XCD L2.
// Chunk-major block order (2048 blocks/chunk). 4 o's per block (1 wave each),
// per-wave LDS idx/W staging; each lane: 4 cols via 8 B bf16x4 loads.
// ---------------------------------------------------------------------------
template<bool OUT_BF16>
__global__ __launch_bounds__(256)
void condensed_relu_g(const unsigned short* __restrict__ h,
                      const int*   __restrict__ idx,
                      const float* __restrict__ W,
                      const float* __restrict__ bm,
                      void* __restrict__ outv)
{
    __shared__ int   sIdx[4][FANIN];
    __shared__ float sW[4][FANIN];

    const int w     = threadIdx.x >> 6;
    const int lane  = threadIdx.x & 63;
    const int chunk = blockIdx.x >> 11;                 // 2048 blocks/chunk
    const int o     = ((blockIdx.x & 2047) << 2) + w;
    const int bOff  = chunk * BCH + lane * 4;

    sIdx[w][lane] = idx[(size_t)o * FANIN + lane];
    sW[w][lane]   = W[(size_t)o * FANIN + lane];
    __syncthreads();

    float a0 = 0.f, a1 = 0.f, a2 = 0.f, a3 = 0.f;
    #pragma unroll 8
    for (int f = 0; f < FANIN; ++f) {
        const int   j  = sIdx[w][f];
        const float wv = sW[w][f];
        const bf16x4 hv = *(const bf16x4*)&h[(size_t)j * B_SZ + bOff];
        a0 += wv * bf2f((unsigned short)hv[0]);
        a1 += wv * bf2f((unsigned short)hv[1]);
        a2 += wv * bf2f((unsigned short)hv[2]);
        a3 += wv * bf2f((unsigned short)hv[3]);
    }
    const float bb = bm[o];
    a0 = fmaxf(a0 + bb, 0.f);
    a1 = fmaxf(a1 + bb, 0.f);
    a2 = fmaxf(a2 + bb, 0.f);
    a3 = fmaxf(a3 + bb, 0.f);

    if (OUT_BF16) {
        bf16x4 ov;
        ov[0] = (short)f2bf(a0); ov[1] = (short)f2bf(a1);
        ov[2] = (short)f2bf(a2); ov[3] = (short)f2bf(a3);
        *(bf16x4*)&((unsigned short*)outv)[(size_t)o * B_SZ + bOff] = ov;
    } else {
        float4 ov; ov.x = a0; ov.y = a1; ov.z = a2; ov.w = a3;
        *(float4*)&((float*)outv)[(size_t)o * B_SZ + bOff] = ov;
    }
}

// ---------------------------------------------------------------------------
// Reduce split-K partials + bias: y[b,n] = sum_s P[s,b,n] + b_out[n]
// P has padded col stride N_OUTP.
// ---------------------------------------------------------------------------
__global__ __launch_bounds__(256)
void reduce_out(const float* __restrict__ P,
                const float* __restrict__ b_out,
                float* __restrict__ y)
{
    const int i = blockIdx.x * 256 + threadIdx.x;
    if (i >= (B_SZ * N_OUT) / 4) return;
    const int e = i * 4;
    const int b = e / N_OUT;
    const int n = e - b * N_OUT;                  // multiple of 4

    float4 acc = *(const float4*)&b_out[n];
    #pragma unroll
    for (int s = 0; s < SPLITK; ++s) {
        const float4 p = *(const float4*)&P[((size_t)s * B_SZ + b) * N_OUTP + n];
        acc.x += p.x; acc.y += p.y; acc.z += p.z; acc.w += p.w;
    }
    *(float4*)&y[e] = acc;
}

// ---------------------------------------------------------------------------
extern "C" void kernel_launch(void* const* d_in, const int* in_sizes, int n_in,
                              void* d_out, int out_size, void* d_ws, size_t ws_size,
                              hipStream_t stream)
{
    const float* x      = (const float*)d_in[0];  // (512, 1024)
    const float* W_in   = (const float*)d_in[1];  // (8192, 1024)
    const float* b_in   = (const float*)d_in[2];  // (8192)
    const float* W_mid  = (const float*)d_in[3];  // (2, 8192, 64)
    const float* b_mid  = (const float*)d_in[4];  // (2, 8192)
    const float* W_out  = (const float*)d_in[5];  // (1000, 8192)
    const float* b_out  = (const float*)d_in[6];  // (1000)
    const int*   indx   = (const int*)d_in[7];    // (8192, 64)

    float* y = (float*)d_out;                     // (512, 1000)

    // ---- workspace layout ----
    char* w = (char*)d_ws;
    unsigned short* hA = (unsigned short*)w; w += (size_t)N_MID * B_SZ * 2;  // 8.4 MB (bf16)
    unsigned short* hB = (unsigned short*)w; w += (size_t)N_MID * B_SZ * 2;  // 8.4 MB (bf16)
    float* hC   = (float*)w;                 w += (size_t)N_MID * B_SZ * 4;  // 16.8 MB (fp32)
    float* P    = (float*)w;                 w += (size_t)SPLITK * B_SZ * N_OUTP * 4; // 16.8 MB
    short* Whi  = (short*)w;                 w += (size_t)N_MID * N_IN * 2;  // 16.8 MB (W_in; reused for W_out)
    short* Wlo  = (short*)w;                 w += (size_t)N_MID * N_IN * 2;  // 16.8 MB
    short* xhi  = (short*)w;                 w += (size_t)B_SZ * N_IN * 2;   // 1.05 MB
    short* xlo  = (short*)w;                 w += (size_t)B_SZ * N_IN * 2;   // 1.05 MB
    short* hthi = (short*)w;                 w += (size_t)B_SZ * N_MID * 2;  // 8.4 MB
    short* htlo = (short*)w;                 w += (size_t)B_SZ * N_MID * 2;  // 8.4 MB
    // total ~94.5 MB

    const int KT1 = N_IN / 32;    // 32 k-frags (GEMM1)
    const int KT3 = N_MID / 32;   // 256 k-frags (GEMM3)

    // 1) conversions for GEMM1
    {
        const int nf = (N_MID / 16) * KT1;   // 16384
        conv_nt<<<nf / 4, 256, 0, stream>>>(W_in, N_MID, N_IN, KT1, Whi, Wlo, nf);
    }
    {
        const int nf = (B_SZ / 16) * KT1;    // 1024
        conv_nt<<<nf / 4, 256, 0, stream>>>(x, B_SZ, N_IN, KT1, xhi, xlo, nf);
    }

    // 2) GEMM1: hA[m, b] = relu(W_in x^T + b_in)  (bf16 output)
    {
        dim3 g(N_MID / 64, B_SZ / 64, 1);    // 128 x 8 = 1024 blocks
        gemm_hilo<true, true><<<g, 256, 0, stream>>>(Whi, Wlo, xhi, xlo, b_in, hA,
                                                     KT1, KT1, 0, B_SZ);
    }

    // 3) condensed layers (bf16 gather, chunked for L2 residency)
    condensed_relu_g<true><<<NCHUNK * 2048, 256, 0, stream>>>(hA, indx, W_mid, b_mid, hB);
    condensed_relu_g<false><<<NCHUNK * 2048, 256, 0, stream>>>(hB, indx,
                                              W_mid + (size_t)N_MID * FANIN,
                                              b_mid + N_MID, hC);

    // 4) conversions for GEMM3: hC^T (transpose) and W_out (padded rows)
    {
        const int nf = (B_SZ / 16) * KT3;    // 8192
        conv_t<<<nf / 4, 256, 0, stream>>>(hC, B_SZ, KT3, hthi, htlo, nf);
    }
    {
        const int nf = (N_OUTP / 16) * KT3;  // 16384
        conv_nt<<<nf / 4, 256, 0, stream>>>(W_out, N_OUT, N_MID, KT3, Whi, Wlo, nf);
    }

    // 5) GEMM3 split-K: P[s, b, n] = partial sums (A = hC^T frags, B = W_out frags)
    {
        dim3 g(B_SZ / 64, N_OUTP / 64, SPLITK);   // 8 x 16 x 8 = 1024 blocks
        gemm_hilo<false, false><<<g, 256, 0, stream>>>(hthi, htlo, Whi, Wlo, nullptr, P,
                                                       KT3, KT3 / SPLITK,
                                                       (size_t)B_SZ * N_OUTP, N_OUTP);
    }

    // 6) reduce + bias
    reduce_out<<<(B_SZ * N_OUT / 4 + 255) / 256, 256, 0, stream>>>(P, b_out, y);
}

// Round 8
// 241.266 us; speedup vs baseline: 2.4420x; 1.2270x over previous
//
#include <hip/hip_runtime.h>

#define B_SZ   512
#define N_IN   1024
#define N_MID  8192
#define N_OUT  1000
#define N_OUTP 1024          // padded
#define FANIN  64
#define SPLITK 8
#define NCHUNK 2
#define BCH    (B_SZ / NCHUNK)   // 256 cols -> 8192*256*2B = 4 MB bf16 slice == one XCD L2

typedef __attribute__((ext_vector_type(8))) short bf16x8;
typedef __attribute__((ext_vector_type(4))) short bf16x4;
typedef __attribute__((ext_vector_type(4))) float f32x4;

static __device__ __forceinline__ unsigned short f2bf(float f) {
    unsigned u = __float_as_uint(f);
    unsigned r = u + 0x7FFF + ((u >> 16) & 1);   // round-to-nearest-even
    return (unsigned short)(r >> 16);
}
static __device__ __forceinline__ float bf2f(unsigned short h) {
    return __uint_as_float(((unsigned)h) << 16);
}

// ---------------------------------------------------------------------------
// Convert fp32 (R x K, row-major, K-inner) -> bf16 MFMA fragments.
// Fragment (mt,kt): lane l holds (m = mt*16 + (l&15), k = kt*32 + (l>>4)*8+j).
// Rows >= R zero-padded.
// ---------------------------------------------------------------------------
__global__ __launch_bounds__(256)
void conv_nt(const float* __restrict__ src, int R, int K, int KT,
             short* __restrict__ dst, int nfrag)
{
    const int wid = threadIdx.x >> 6, lane = threadIdx.x & 63;
    const int fid = blockIdx.x * 4 + wid;
    if (fid >= nfrag) return;
    const int mt = fid / KT, kt = fid - mt * KT;
    const int m = mt * 16 + (lane & 15);
    const int k = kt * 32 + (lane >> 4) * 8;

    float v[8];
    if (m < R) {
        const float4 a = *(const float4*)(src + (size_t)m * K + k);
        const float4 b = *(const float4*)(src + (size_t)m * K + k + 4);
        v[0]=a.x; v[1]=a.y; v[2]=a.z; v[3]=a.w;
        v[4]=b.x; v[5]=b.y; v[6]=b.z; v[7]=b.w;
    } else {
        #pragma unroll
        for (int j = 0; j < 8; ++j) v[j] = 0.f;
    }
    bf16x8 vh;
    #pragma unroll
    for (int j = 0; j < 8; ++j) vh[j] = (short)f2bf(v[j]);
    *(bf16x8*)(dst + (size_t)fid * 512 + lane * 8) = vh;
}

// ---------------------------------------------------------------------------
// Transpose bf16 (K x Bcols, k-major) -> fragments of src^T (Bcols x K).
// Pure bit copy (input already bf16).
// ---------------------------------------------------------------------------
__global__ __launch_bounds__(256)
void conv_t_bf16(const unsigned short* __restrict__ src, int Bc, int KT,
                 short* __restrict__ dst, int nfrag)
{
    const int wid = threadIdx.x >> 6, lane = threadIdx.x & 63;
    const int fid = blockIdx.x * 4 + wid;
    if (fid >= nfrag) return;
    const int bt = fid / KT, kt = fid - bt * KT;
    const int b = bt * 16 + (lane & 15);
    const int k = kt * 32 + (lane >> 4) * 8;

    bf16x8 v;
    #pragma unroll
    for (int j = 0; j < 8; ++j)
        v[j] = (short)src[(size_t)(k + j) * Bc + b];
    *(bf16x8*)(dst + (size_t)fid * 512 + lane * 8) = v;
}

// ---------------------------------------------------------------------------
// Fragment-direct bf16 MFMA GEMM, XCD-swizzled 1D grid of 1024 blocks.
// D[m,n] = sum_k A[m,k]*B[n,k] (K-inner pre-swizzled frags).
// 4 waves 2x2; block tile 64x64; wave tile 32x32 (acc[2][2]); K-step 32.
// MODE 1 (GEMM1): lm=16*(f&7)+((f>>3)&15), ln=f>>7 -> XCD k owns m-tiles
//   [16k,16k+16) x all n: per-XCD set = 2.1 MB A + 2.1 MB B ~ L2-resident.
// MODE 3 (GEMM3 split-K): s=f>>7 (K-slice), w=f&127, lm=w>>4 (b-tile),
//   ln=w&15 (n-tile); per-split slice 3.1 MB < L2.
// ---------------------------------------------------------------------------
template<int MODE, bool RELU, bool OBF16>
__global__ __launch_bounds__(256)
void gemm_bf16(const short* __restrict__ A, const short* __restrict__ Bm,
               const float* __restrict__ bias,   // per-m, only when RELU
               void* __restrict__ Cv,
               int KT, size_t csliceStride, int ldc)
{
    const int lane = threadIdx.x & 63;
    const int wid  = threadIdx.x >> 6;
    const int wm = wid & 1, wn = wid >> 1;
    const int f = blockIdx.x;

    int lm, ln, ktBeg, ktEnd;
    size_t cbase = 0;
    if (MODE == 1) {
        lm = 16 * (f & 7) + ((f >> 3) & 15);
        ln = f >> 7;
        ktBeg = 0; ktEnd = KT;
    } else {
        const int s = f >> 7, w = f & 127;
        lm = w >> 4;
        ln = w & 15;
        ktBeg = s * 32; ktEnd = ktBeg + 32;
        cbase = (size_t)s * csliceStride;
    }
    const int mt0 = lm * 4 + wm * 2;
    const int nt0 = ln * 4 + wn * 2;

    f32x4 acc[2][2] = {};
    const size_t laneOff = (size_t)lane * 8;

    #pragma unroll 4
    for (int kt = ktBeg; kt < ktEnd; ++kt) {
        bf16x8 a[2], b[2];
        #pragma unroll
        for (int i = 0; i < 2; ++i)
            a[i] = *(const bf16x8*)(A + ((size_t)(mt0 + i) * KT + kt) * 512 + laneOff);
        #pragma unroll
        for (int j = 0; j < 2; ++j)
            b[j] = *(const bf16x8*)(Bm + ((size_t)(nt0 + j) * KT + kt) * 512 + laneOff);
        #pragma unroll
        for (int i = 0; i < 2; ++i)
            #pragma unroll
            for (int j = 0; j < 2; ++j)
                acc[i][j] = __builtin_amdgcn_mfma_f32_16x16x32_bf16(a[i], b[j], acc[i][j], 0, 0, 0);
    }

    // C/D layout: col = lane&15, row = (lane>>4)*4 + r   [measured m89/m91]
    const int col = lane & 15;
    const int rb  = (lane >> 4) * 4;
    #pragma unroll
    for (int i = 0; i < 2; ++i) {
        #pragma unroll
        for (int r = 0; r < 4; ++r) {
            const int m = (mt0 + i) * 16 + rb + r;
            float bv = 0.f;
            if (RELU) bv = bias[m];
            #pragma unroll
            for (int j = 0; j < 2; ++j) {
                const int n = (nt0 + j) * 16 + col;
                float v = acc[i][j][r] + bv;
                if (RELU) v = fmaxf(v, 0.f);
                if (OBF16)
                    ((unsigned short*)Cv)[cbase + (size_t)m * ldc + n] = f2bf(v);
                else
                    ((float*)Cv)[cbase + (size_t)m * ldc + n] = v;
            }
        }
    }
}

// ---------------------------------------------------------------------------
// Condensed layer, bf16 gather, B-chunked for L2 residency:
// out[o, b] = relu( sum_f W[o,f] * h[idx[o,f], b] + bm[o] )
// h: (N_MID, B_SZ) bf16. Chunk = 256 cols -> 4 MB slice per XCD L2.
// Chunk-major block order (2048 blocks/chunk). 4 o's per block (1 wave each).
// ---------------------------------------------------------------------------
__global__ __launch_bounds__(256)
void condensed_relu_g(const unsigned short* __restrict__ h,
                      const int*   __restrict__ idx,
                      const float* __restrict__ W,
                      const float* __restrict__ bm,
                      unsigned short* __restrict__ outv)
{
    __shared__ int   sIdx[4][FANIN];
    __shared__ float sW[4][FANIN];

    const int w     = threadIdx.x >> 6;
    const int lane  = threadIdx.x & 63;
    const int chunk = blockIdx.x >> 11;                 // 2048 blocks/chunk
    const int o     = ((blockIdx.x & 2047) << 2) + w;
    const int bOff  = chunk * BCH + lane * 4;

    sIdx[w][lane] = idx[(size_t)o * FANIN + lane];
    sW[w][lane]   = W[(size_t)o * FANIN + lane];
    __syncthreads();

    float a0 = 0.f, a1 = 0.f, a2 = 0.f, a3 = 0.f;
    #pragma unroll 8
    for (int f = 0; f < FANIN; ++f) {
        const int   j  = sIdx[w][f];
        const float wv = sW[w][f];
        const bf16x4 hv = *(const bf16x4*)&h[(size_t)j * B_SZ + bOff];
        a0 += wv * bf2f((unsigned short)hv[0]);
        a1 += wv * bf2f((unsigned short)hv[1]);
        a2 += wv * bf2f((unsigned short)hv[2]);
        a3 += wv * bf2f((unsigned short)hv[3]);
    }
    const float bb = bm[o];
    a0 = fmaxf(a0 + bb, 0.f);
    a1 = fmaxf(a1 + bb, 0.f);
    a2 = fmaxf(a2 + bb, 0.f);
    a3 = fmaxf(a3 + bb, 0.f);

    bf16x4 ov;
    ov[0] = (short)f2bf(a0); ov[1] = (short)f2bf(a1);
    ov[2] = (short)f2bf(a2); ov[3] = (short)f2bf(a3);
    *(bf16x4*)&outv[(size_t)o * B_SZ + bOff] = ov;
}

// ---------------------------------------------------------------------------
// Reduce split-K partials + bias: y[b,n] = sum_s P[s,b,n] + b_out[n]
// ---------------------------------------------------------------------------
__global__ __launch_bounds__(256)
void reduce_out(const float* __restrict__ P,
                const float* __restrict__ b_out,
                float* __restrict__ y)
{
    const int i = blockIdx.x * 256 + threadIdx.x;
    if (i >= (B_SZ * N_OUT) / 4) return;
    const int e = i * 4;
    const int b = e / N_OUT;
    const int n = e - b * N_OUT;                  // multiple of 4

    float4 acc = *(const float4*)&b_out[n];
    #pragma unroll
    for (int s = 0; s < SPLITK; ++s) {
        const float4 p = *(const float4*)&P[((size_t)s * B_SZ + b) * N_OUTP + n];
        acc.x += p.x; acc.y += p.y; acc.z += p.z; acc.w += p.w;
    }
    *(float4*)&y[e] = acc;
}

// ---------------------------------------------------------------------------
extern "C" void kernel_launch(void* const* d_in, const int* in_sizes, int n_in,
                              void* d_out, int out_size, void* d_ws, size_t ws_size,
                              hipStream_t stream)
{
    const float* x      = (const float*)d_in[0];  // (512, 1024)
    const float* W_in   = (const float*)d_in[1];  // (8192, 1024)
    const float* b_in   = (const float*)d_in[2];  // (8192)
    const float* W_mid  = (const float*)d_in[3];  // (2, 8192, 64)
    const float* b_mid  = (const float*)d_in[4];  // (2, 8192)
    const float* W_out  = (const float*)d_in[5];  // (1000, 8192)
    const float* b_out  = (const float*)d_in[6];  // (1000)
    const int*   indx   = (const int*)d_in[7];    // (8192, 64)

    float* y = (float*)d_out;                     // (512, 1000)

    // ---- workspace layout ----
    char* w = (char*)d_ws;
    unsigned short* hA = (unsigned short*)w; w += (size_t)N_MID * B_SZ * 2;  // 8.4 MB
    unsigned short* hB = (unsigned short*)w; w += (size_t)N_MID * B_SZ * 2;  // 8.4 MB
    unsigned short* hC = (unsigned short*)w; w += (size_t)N_MID * B_SZ * 2;  // 8.4 MB
    float* P    = (float*)w;                 w += (size_t)SPLITK * B_SZ * N_OUTP * 4; // 16.8 MB
    short* Wb   = (short*)w;                 w += (size_t)N_MID * N_IN * 2;  // 16.8 MB (W_in; reused for W_out)
    short* xb   = (short*)w;                 w += (size_t)B_SZ * N_IN * 2;   // 1.05 MB
    short* htb  = (short*)w;                 w += (size_t)B_SZ * N_MID * 2;  // 8.4 MB
    // total ~68.3 MB

    const int KT1 = N_IN / 32;    // 32 k-frags (GEMM1)
    const int KT3 = N_MID / 32;   // 256 k-frags (GEMM3)

    // 1) conversions for GEMM1
    {
        const int nf = (N_MID / 16) * KT1;   // 16384
        conv_nt<<<nf / 4, 256, 0, stream>>>(W_in, N_MID, N_IN, KT1, Wb, nf);
    }
    {
        const int nf = (B_SZ / 16) * KT1;    // 1024
        conv_nt<<<nf / 4, 256, 0, stream>>>(x, B_SZ, N_IN, KT1, xb, nf);
    }

    // 2) GEMM1: hA[m, b] = relu(W_in x^T + b_in)  (bf16 out, XCD-swizzled)
    gemm_bf16<1, true, true><<<1024, 256, 0, stream>>>(Wb, xb, b_in, hA,
                                                       KT1, 0, B_SZ);

    // 3) condensed layers (bf16 gather, chunked for L2 residency)
    condensed_relu_g<<<NCHUNK * 2048, 256, 0, stream>>>(hA, indx, W_mid, b_mid, hB);
    condensed_relu_g<<<NCHUNK * 2048, 256, 0, stream>>>(hB, indx,
                                              W_mid + (size_t)N_MID * FANIN,
                                              b_mid + N_MID, hC);

    // 4) conversions for GEMM3: hC^T (bit-transpose) and W_out (padded rows)
    {
        const int nf = (B_SZ / 16) * KT3;    // 8192
        conv_t_bf16<<<nf / 4, 256, 0, stream>>>(hC, B_SZ, KT3, htb, nf);
    }
    {
        const int nf = (N_OUTP / 16) * KT3;  // 16384
        conv_nt<<<nf / 4, 256, 0, stream>>>(W_out, N_OUT, N_MID, KT3, Wb, nf);
    }

    // 5) GEMM3 split-K (1024 blocks = 8 splits x 128)
    gemm_bf16<3, false, false><<<1024, 256, 0, stream>>>(htb, Wb, nullptr, P,
                                                         KT3, (size_t)B_SZ * N_OUTP,
                                                         N_OUTP);

    // 6) reduce + bias
    reduce_out<<<(B_SZ * N_OUT / 4 + 255) / 256, 256, 0, stream>>>(P, b_out, y);
}

// Round 11
// 240.830 us; speedup vs baseline: 2.4465x; 1.0018x over previous
//
#include <hip/hip_runtime.h>

#define B_SZ   512
#define N_IN   1024
#define N_MID  8192
#define N_OUT  1000
#define N_OUTP 1024          // padded
#define FANIN  64
#define SPLITK 8
#define NCHUNK 2
#define BCH    (B_SZ / NCHUNK)   // 256 cols -> 8192*256*2B = 4 MB bf16 slice == one XCD L2

typedef __attribute__((ext_vector_type(8))) short bf16x8;
typedef __attribute__((ext_vector_type(4))) short bf16x4;
typedef __attribute__((ext_vector_type(4))) float f32x4;

static __device__ __forceinline__ unsigned short f2bf(float f) {
    unsigned u = __float_as_uint(f);
    unsigned r = u + 0x7FFF + ((u >> 16) & 1);   // round-to-nearest-even
    return (unsigned short)(r >> 16);
}
static __device__ __forceinline__ float bf2f(unsigned short h) {
    return __uint_as_float(((unsigned)h) << 16);
}

// ---------------------------------------------------------------------------
// Convert fp32 (R x K, row-major, K-inner) -> bf16 MFMA fragments.
// Fragment (mt,kt): lane l holds (m = mt*16 + (l&15), k = kt*32 + (l>>4)*8+j).
// Rows >= R zero-padded.
// ---------------------------------------------------------------------------
__global__ __launch_bounds__(256)
void conv_nt(const float* __restrict__ src, int R, int K, int KT,
             short* __restrict__ dst, int nfrag)
{
    const int wid = threadIdx.x >> 6, lane = threadIdx.x & 63;
    const int fid = blockIdx.x * 4 + wid;
    if (fid >= nfrag) return;
    const int mt = fid / KT, kt = fid - mt * KT;
    const int m = mt * 16 + (lane & 15);
    const int k = kt * 32 + (lane >> 4) * 8;

    float v[8];
    if (m < R) {
        const float4 a = *(const float4*)(src + (size_t)m * K + k);
        const float4 b = *(const float4*)(src + (size_t)m * K + k + 4);
        v[0]=a.x; v[1]=a.y; v[2]=a.z; v[3]=a.w;
        v[4]=b.x; v[5]=b.y; v[6]=b.z; v[7]=b.w;
    } else {
        #pragma unroll
        for (int j = 0; j < 8; ++j) v[j] = 0.f;
    }
    bf16x8 vh;
    #pragma unroll
    for (int j = 0; j < 8; ++j) vh[j] = (short)f2bf(v[j]);
    *(bf16x8*)(dst + (size_t)fid * 512 + lane * 8) = vh;
}

// ---------------------------------------------------------------------------
// Transpose bf16 (K x Bcols, k-major) -> fragments of src^T (Bcols x K).
// ---------------------------------------------------------------------------
__global__ __launch_bounds__(256)
void conv_t_bf16(const unsigned short* __restrict__ src, int Bc, int KT,
                 short* __restrict__ dst, int nfrag)
{
    const int wid = threadIdx.x >> 6, lane = threadIdx.x & 63;
    const int fid = blockIdx.x * 4 + wid;
    if (fid >= nfrag) return;
    const int bt = fid / KT, kt = fid - bt * KT;
    const int b = bt * 16 + (lane & 15);
    const int k = kt * 32 + (lane >> 4) * 8;

    bf16x8 v;
    #pragma unroll
    for (int j = 0; j < 8; ++j)
        v[j] = (short)src[(size_t)(k + j) * Bc + b];
    *(bf16x8*)(dst + (size_t)fid * 512 + lane * 8) = v;
}

// ---------------------------------------------------------------------------
// Fragment-direct bf16 MFMA GEMM, XCD-swizzled 1D grid of 512 blocks.
// D[m,n] = sum_k A[m,k]*B[n,k] (K-inner pre-swizzled frags).
// Block: 4 waves in 2x2; block tile 64(m) x 128(n); wave tile 32x64
// (acc[2][4] -> 0.75 KB fragment bytes per MFMA, vs 1.0 at 32x32).
// MODE 1 (GEMM1, 512 blocks): xcd=f&7, i=f>>3; ln=i&3, lm=xcd*16+(i>>2).
//   Per-XCD: A m-slice 2.1 MB + B 1 MB resident in 4 MB L2.
// MODE 3 (GEMM3 split-K, 512 blocks): ln=f&7, s=(f>>3)&7, lm=f>>6.
//   Per-XCD: B n-slice 2.1 MB resident; A split-slices stream via L3.
// ---------------------------------------------------------------------------
template<int MODE, bool RELU, bool OBF16>
__global__ __launch_bounds__(256)
void gemm_bf16(const short* __restrict__ A, const short* __restrict__ Bm,
               const float* __restrict__ bias,   // per-m, only when RELU
               void* __restrict__ Cv,
               int KT, size_t csliceStride, int ldc)
{
    const int lane = threadIdx.x & 63;
    const int wid  = threadIdx.x >> 6;
    const int wm = wid & 1, wn = wid >> 1;
    const int f = blockIdx.x;

    int lm, ln, ktBeg, ktEnd;
    size_t cbase = 0;
    if (MODE == 1) {
        const int xcd = f & 7, i = f >> 3;
        ln = i & 3;
        lm = xcd * 16 + (i >> 2);
        ktBeg = 0; ktEnd = KT;
    } else {
        ln = f & 7;
        const int s = (f >> 3) & 7;
        lm = f >> 6;
        ktBeg = s * 32; ktEnd = ktBeg + 32;
        cbase = (size_t)s * csliceStride;
    }
    const int mt0 = lm * 4 + wm * 2;
    const int nt0 = ln * 8 + wn * 4;

    f32x4 acc[2][4] = {};
    const size_t laneOff = (size_t)lane * 8;

    #pragma unroll 4
    for (int kt = ktBeg; kt < ktEnd; ++kt) {
        bf16x8 a[2], b[4];
        #pragma unroll
        for (int i = 0; i < 2; ++i)
            a[i] = *(const bf16x8*)(A + ((size_t)(mt0 + i) * KT + kt) * 512 + laneOff);
        #pragma unroll
        for (int j = 0; j < 4; ++j)
            b[j] = *(const bf16x8*)(Bm + ((size_t)(nt0 + j) * KT + kt) * 512 + laneOff);
        #pragma unroll
        for (int i = 0; i < 2; ++i)
            #pragma unroll
            for (int j = 0; j < 4; ++j)
                acc[i][j] = __builtin_amdgcn_mfma_f32_16x16x32_bf16(a[i], b[j], acc[i][j], 0, 0, 0);
    }

    // C/D layout: col = lane&15, row = (lane>>4)*4 + r   [measured m89/m91]
    const int col = lane & 15;
    const int rb  = (lane >> 4) * 4;
    #pragma unroll
    for (int i = 0; i < 2; ++i) {
        #pragma unroll
        for (int r = 0; r < 4; ++r) {
            const int m = (mt0 + i) * 16 + rb + r;
            float bv = 0.f;
            if (RELU) bv = bias[m];
            #pragma unroll
            for (int j = 0; j < 4; ++j) {
                const int n = (nt0 + j) * 16 + col;
                float v = acc[i][j][r] + bv;
                if (RELU) v = fmaxf(v, 0.f);
                if (OBF16)
                    ((unsigned short*)Cv)[cbase + (size_t)m * ldc + n] = f2bf(v);
                else
                    ((float*)Cv)[cbase + (size_t)m * ldc + n] = v;
            }
        }
    }
}

// ---------------------------------------------------------------------------
// Condensed layer, bf16 gather, B-chunked for L2 residency.
// out[o, b] = relu( sum_f W[o,f] * h[idx[o,f], b] + bm[o] )
// SGPR-ized: idx/W are wave-uniform -> readfirstlane puts the row index and
// weight in SGPRs; the gather becomes global_load(SGPR base + small voffset),
// freeing VGPRs/VALU for a 16-deep load pipeline.
// ---------------------------------------------------------------------------
__global__ __launch_bounds__(256)
void condensed_relu_g(const unsigned short* __restrict__ h,
                      const int*   __restrict__ idx,
                      const float* __restrict__ W,
                      const float* __restrict__ bm,
                      unsigned short* __restrict__ outv)
{
    __shared__ int   sIdx[4][FANIN];
    __shared__ float sW[4][FANIN];

    const int w     = threadIdx.x >> 6;
    const int lane  = threadIdx.x & 63;
    const int chunk = blockIdx.x >> 11;                 // 2048 blocks/chunk
    const int o     = ((blockIdx.x & 2047) << 2) + w;
    const int bOff  = chunk * BCH + lane * 4;

    sIdx[w][lane] = idx[(size_t)o * FANIN + lane];
    sW[w][lane]   = W[(size_t)o * FANIN + lane];
    __syncthreads();

    const unsigned short* hbase = h + bOff;   // per-lane, loop-invariant

    float a0 = 0.f, a1 = 0.f, a2 = 0.f, a3 = 0.f;
    #pragma unroll 16
    for (int f = 0; f < FANIN; ++f) {
        const int   j  = __builtin_amdgcn_readfirstlane(sIdx[w][f]);
        const float wv = __uint_as_float(
            __builtin_amdgcn_readfirstlane(__float_as_uint(sW[w][f])));
        const uint2 u = *(const uint2*)(hbase + (size_t)j * B_SZ);
        a0 = fmaf(wv, __uint_as_float(u.x << 16), a0);
        a1 = fmaf(wv, __uint_as_float(u.x & 0xffff0000u), a1);
        a2 = fmaf(wv, __uint_as_float(u.y << 16), a2);
        a3 = fmaf(wv, __uint_as_float(u.y & 0xffff0000u), a3);
    }
    const float bb = bm[o];
    a0 = fmaxf(a0 + bb, 0.f);
    a1 = fmaxf(a1 + bb, 0.f);
    a2 = fmaxf(a2 + bb, 0.f);
    a3 = fmaxf(a3 + bb, 0.f);

    bf16x4 ov;
    ov[0] = (short)f2bf(a0); ov[1] = (short)f2bf(a1);
    ov[2] = (short)f2bf(a2); ov[3] = (short)f2bf(a3);
    *(bf16x4*)&outv[(size_t)o * B_SZ + bOff] = ov;
}

// ---------------------------------------------------------------------------
// Reduce split-K partials + bias: y[b,n] = sum_s P[s,b,n] + b_out[n]
// ---------------------------------------------------------------------------
__global__ __launch_bounds__(256)
void reduce_out(const float* __restrict__ P,
                const float* __restrict__ b_out,
                float* __restrict__ y)
{
    const int i = blockIdx.x * 256 + threadIdx.x;
    if (i >= (B_SZ * N_OUT) / 4) return;
    const int e = i * 4;
    const int b = e / N_OUT;
    const int n = e - b * N_OUT;                  // multiple of 4

    float4 acc = *(const float4*)&b_out[n];
    #pragma unroll
    for (int s = 0; s < SPLITK; ++s) {
        const float4 p = *(const float4*)&P[((size_t)s * B_SZ + b) * N_OUTP + n];
        acc.x += p.x; acc.y += p.y; acc.z += p.z; acc.w += p.w;
    }
    *(float4*)&y[e] = acc;
}

// ---------------------------------------------------------------------------
extern "C" void kernel_launch(void* const* d_in, const int* in_sizes, int n_in,
                              void* d_out, int out_size, void* d_ws, size_t ws_size,
                              hipStream_t stream)
{
    const float* x      = (const float*)d_in[0];  // (512, 1024)
    const float* W_in   = (const float*)d_in[1];  // (8192, 1024)
    const float* b_in   = (const float*)d_in[2];  // (8192)
    const float* W_mid  = (const float*)d_in[3];  // (2, 8192, 64)
    const float* b_mid  = (const float*)d_in[4];  // (2, 8192)
    const float* W_out  = (const float*)d_in[5];  // (1000, 8192)
    const float* b_out  = (const float*)d_in[6];  // (1000)
    const int*   indx   = (const int*)d_in[7];    // (8192, 64)

    float* y = (float*)d_out;                     // (512, 1000)

    // ---- workspace layout ----
    char* w = (char*)d_ws;
    unsigned short* hA = (unsigned short*)w; w += (size_t)N_MID * B_SZ * 2;  // 8.4 MB
    unsigned short* hB = (unsigned short*)w; w += (size_t)N_MID * B_SZ * 2;  // 8.4 MB
    unsigned short* hC = (unsigned short*)w; w += (size_t)N_MID * B_SZ * 2;  // 8.4 MB
    float* P    = (float*)w;                 w += (size_t)SPLITK * B_SZ * N_OUTP * 4; // 16.8 MB
    short* Wb   = (short*)w;                 w += (size_t)N_MID * N_IN * 2;  // 16.8 MB (W_in; reused for W_out)
    short* xb   = (short*)w;                 w += (size_t)B_SZ * N_IN * 2;   // 1.05 MB
    short* htb  = (short*)w;                 w += (size_t)B_SZ * N_MID * 2;  // 8.4 MB
    // total ~68.3 MB

    const int KT1 = N_IN / 32;    // 32 k-frags (GEMM1)
    const int KT3 = N_MID / 32;   // 256 k-frags (GEMM3)

    // 1) conversions for GEMM1
    {
        const int nf = (N_MID / 16) * KT1;   // 16384
        conv_nt<<<nf / 4, 256, 0, stream>>>(W_in, N_MID, N_IN, KT1, Wb, nf);
    }
    {
        const int nf = (B_SZ / 16) * KT1;    // 1024
        conv_nt<<<nf / 4, 256, 0, stream>>>(x, B_SZ, N_IN, KT1, xb, nf);
    }

    // 2) GEMM1: hA[m, b] = relu(W_in x^T + b_in)  (bf16 out, XCD-swizzled)
    gemm_bf16<1, true, true><<<512, 256, 0, stream>>>(Wb, xb, b_in, hA,
                                                      KT1, 0, B_SZ);

    // 3) condensed layers (bf16 gather, chunked for L2 residency)
    condensed_relu_g<<<NCHUNK * 2048, 256, 0, stream>>>(hA, indx, W_mid, b_mid, hB);
    condensed_relu_g<<<NCHUNK * 2048, 256, 0, stream>>>(hB, indx,
                                              W_mid + (size_t)N_MID * FANIN,
                                              b_mid + N_MID, hC);

    // 4) conversions for GEMM3: hC^T (bit-transpose) and W_out (padded rows)
    {
        const int nf = (B_SZ / 16) * KT3;    // 8192
        conv_t_bf16<<<nf / 4, 256, 0, stream>>>(hC, B_SZ, KT3, htb, nf);
    }
    {
        const int nf = (N_OUTP / 16) * KT3;  // 16384
        conv_nt<<<nf / 4, 256, 0, stream>>>(W_out, N_OUT, N_MID, KT3, Wb, nf);
    }

    // 5) GEMM3 split-K (512 blocks = 8 ln x 8 splits x 8 lm)
    gemm_bf16<3, false, false><<<512, 256, 0, stream>>>(htb, Wb, nullptr, P,
                                                        KT3, (size_t)B_SZ * N_OUTP,
                                                        N_OUTP);

    // 6) reduce + bias
    reduce_out<<<(B_SZ * N_OUT / 4 + 255) / 256, 256, 0, stream>>>(P, b_out, y);
}

// Round 12
// 235.489 us; speedup vs baseline: 2.5019x; 1.0227x over previous
//
#include <hip/hip_runtime.h>

#define B_SZ   512
#define N_IN   1024
#define N_MID  8192
#define N_OUT  1000
#define N_OUTP 1024          // padded
#define FANIN  64
#define SPLITK 8
#define NCHUNK 2
#define BCH    (B_SZ / NCHUNK)   // 256 cols -> 8192*256*2B = 4 MB bf16 slice == one XCD L2

typedef __attribute__((ext_vector_type(8))) short bf16x8;
typedef __attribute__((ext_vector_type(4))) short bf16x4;
typedef __attribute__((ext_vector_type(4))) float f32x4;

static __device__ __forceinline__ unsigned short f2bf(float f) {
    unsigned u = __float_as_uint(f);
    unsigned r = u + 0x7FFF + ((u >> 16) & 1);   // round-to-nearest-even
    return (unsigned short)(r >> 16);
}
static __device__ __forceinline__ float bf2f(unsigned short h) {
    return __uint_as_float(((unsigned)h) << 16);
}

// ---------------------------------------------------------------------------
// Convert fp32 (R x K, row-major, K-inner) -> bf16 MFMA fragments.
// Fragment (mt,kt): lane l holds (m = mt*16 + (l&15), k = kt*32 + (l>>4)*8+j).
// Rows >= R zero-padded.
// ---------------------------------------------------------------------------
__global__ __launch_bounds__(256)
void conv_nt(const float* __restrict__ src, int R, int K, int KT,
             short* __restrict__ dst, int nfrag)
{
    const int wid = threadIdx.x >> 6, lane = threadIdx.x & 63;
    const int fid = blockIdx.x * 4 + wid;
    if (fid >= nfrag) return;
    const int mt = fid / KT, kt = fid - mt * KT;
    const int m = mt * 16 + (lane & 15);
    const int k = kt * 32 + (lane >> 4) * 8;

    float v[8];
    if (m < R) {
        const float4 a = *(const float4*)(src + (size_t)m * K + k);
        const float4 b = *(const float4*)(src + (size_t)m * K + k + 4);
        v[0]=a.x; v[1]=a.y; v[2]=a.z; v[3]=a.w;
        v[4]=b.x; v[5]=b.y; v[6]=b.z; v[7]=b.w;
    } else {
        #pragma unroll
        for (int j = 0; j < 8; ++j) v[j] = 0.f;
    }
    bf16x8 vh;
    #pragma unroll
    for (int j = 0; j < 8; ++j) vh[j] = (short)f2bf(v[j]);
    *(bf16x8*)(dst + (size_t)fid * 512 + lane * 8) = vh;
}

// ---------------------------------------------------------------------------
// Transpose bf16 (K x Bcols, k-major) -> fragments of src^T (Bcols x K).
// ---------------------------------------------------------------------------
__global__ __launch_bounds__(256)
void conv_t_bf16(const unsigned short* __restrict__ src, int Bc, int KT,
                 short* __restrict__ dst, int nfrag)
{
    const int wid = threadIdx.x >> 6, lane = threadIdx.x & 63;
    const int fid = blockIdx.x * 4 + wid;
    if (fid >= nfrag) return;
    const int bt = fid / KT, kt = fid - bt * KT;
    const int b = bt * 16 + (lane & 15);
    const int k = kt * 32 + (lane >> 4) * 8;

    bf16x8 v;
    #pragma unroll
    for (int j = 0; j < 8; ++j)
        v[j] = (short)src[(size_t)(k + j) * Bc + b];
    *(bf16x8*)(dst + (size_t)fid * 512 + lane * 8) = v;
}

// ---------------------------------------------------------------------------
// Fragment-direct bf16 MFMA GEMM, XCD-swizzled 1D grid of 512 blocks.
// D[m,n] = sum_k A[m,k]*B[n,k] (K-inner pre-swizzled frags).
// Block: 4 waves in 2x2; block tile 64(m) x 128(n); wave tile 32x64
// (acc[2][4] -> 0.75 KB fragment bytes per MFMA).
// MODE 1 (GEMM1): per-XCD A m-slice 2.1 MB + B 1 MB resident in L2.
// MODE 3 (GEMM3 split-K): per-XCD B n-slice 2.1 MB resident.
// ---------------------------------------------------------------------------
template<int MODE, bool RELU, bool OBF16>
__global__ __launch_bounds__(256)
void gemm_bf16(const short* __restrict__ A, const short* __restrict__ Bm,
               const float* __restrict__ bias,   // per-m, only when RELU
               void* __restrict__ Cv,
               int KT, size_t csliceStride, int ldc)
{
    const int lane = threadIdx.x & 63;
    const int wid  = threadIdx.x >> 6;
    const int wm = wid & 1, wn = wid >> 1;
    const int f = blockIdx.x;

    int lm, ln, ktBeg, ktEnd;
    size_t cbase = 0;
    if (MODE == 1) {
        const int xcd = f & 7, i = f >> 3;
        ln = i & 3;
        lm = xcd * 16 + (i >> 2);
        ktBeg = 0; ktEnd = KT;
    } else {
        ln = f & 7;
        const int s = (f >> 3) & 7;
        lm = f >> 6;
        ktBeg = s * 32; ktEnd = ktBeg + 32;
        cbase = (size_t)s * csliceStride;
    }
    const int mt0 = lm * 4 + wm * 2;
    const int nt0 = ln * 8 + wn * 4;

    f32x4 acc[2][4] = {};
    const size_t laneOff = (size_t)lane * 8;

    #pragma unroll 4
    for (int kt = ktBeg; kt < ktEnd; ++kt) {
        bf16x8 a[2], b[4];
        #pragma unroll
        for (int i = 0; i < 2; ++i)
            a[i] = *(const bf16x8*)(A + ((size_t)(mt0 + i) * KT + kt) * 512 + laneOff);
        #pragma unroll
        for (int j = 0; j < 4; ++j)
            b[j] = *(const bf16x8*)(Bm + ((size_t)(nt0 + j) * KT + kt) * 512 + laneOff);
        #pragma unroll
        for (int i = 0; i < 2; ++i)
            #pragma unroll
            for (int j = 0; j < 4; ++j)
                acc[i][j] = __builtin_amdgcn_mfma_f32_16x16x32_bf16(a[i], b[j], acc[i][j], 0, 0, 0);
    }

    // C/D layout: col = lane&15, row = (lane>>4)*4 + r   [measured m89/m91]
    const int col = lane & 15;
    const int rb  = (lane >> 4) * 4;
    #pragma unroll
    for (int i = 0; i < 2; ++i) {
        #pragma unroll
        for (int r = 0; r < 4; ++r) {
            const int m = (mt0 + i) * 16 + rb + r;
            float bv = 0.f;
            if (RELU) bv = bias[m];
            #pragma unroll
            for (int j = 0; j < 4; ++j) {
                const int n = (nt0 + j) * 16 + col;
                float v = acc[i][j][r] + bv;
                if (RELU) v = fmaxf(v, 0.f);
                if (OBF16)
                    ((unsigned short*)Cv)[cbase + (size_t)m * ldc + n] = f2bf(v);
                else
                    ((float*)Cv)[cbase + (size_t)m * ldc + n] = v;
            }
        }
    }
}

// ---------------------------------------------------------------------------
// Condensed layer, bf16 gather, B-chunked for L2 residency.
// out[o, b] = relu( sum_f W[o,f] * h[idx[o,f], b] + bm[o] )
// Software-pipelined gather: 4 fully-unrolled batches of 16 uint2 loads,
// batch k+1 issued BEFORE batch k is consumed (vmcnt keeps 16 in flight
// across the consume). All array indices static -> registers (rule #20).
// Fixes round-11 serialization (VGPR=20 -> compiler drained vmcnt(0)/iter).
// ---------------------------------------------------------------------------
__global__ __launch_bounds__(256)
void condensed_relu_g(const unsigned short* __restrict__ h,
                      const int*   __restrict__ idx,
                      const float* __restrict__ W,
                      const float* __restrict__ bm,
                      unsigned short* __restrict__ outv)
{
    __shared__ int   sIdx[4][FANIN];
    __shared__ float sW[4][FANIN];

    const int w     = threadIdx.x >> 6;
    const int lane  = threadIdx.x & 63;
    const int chunk = blockIdx.x >> 11;                 // 2048 blocks/chunk
    const int o     = ((blockIdx.x & 2047) << 2) + w;
    const int bOff  = chunk * BCH + lane * 4;

    sIdx[w][lane] = idx[(size_t)o * FANIN + lane];
    sW[w][lane]   = W[(size_t)o * FANIN + lane];
    __syncthreads();

    const unsigned short* hbase = h + bOff;   // per-lane, loop-invariant

    float a0 = 0.f, a1 = 0.f, a2 = 0.f, a3 = 0.f;

    uint2 u[16];
    #pragma unroll
    for (int q = 0; q < 16; ++q) {
        const int j = __builtin_amdgcn_readfirstlane(sIdx[w][q]);
        u[q] = *(const uint2*)(hbase + (size_t)j * B_SZ);
    }

    #pragma unroll
    for (int fb = 0; fb < 4; ++fb) {
        uint2 v[16];
        if (fb < 3) {
            #pragma unroll
            for (int q = 0; q < 16; ++q) {
                const int j = __builtin_amdgcn_readfirstlane(sIdx[w][(fb + 1) * 16 + q]);
                v[q] = *(const uint2*)(hbase + (size_t)j * B_SZ);
            }
        }
        #pragma unroll
        for (int q = 0; q < 16; ++q) {
            const float wv = __uint_as_float(
                __builtin_amdgcn_readfirstlane(__float_as_uint(sW[w][fb * 16 + q])));
            a0 = fmaf(wv, __uint_as_float(u[q].x << 16), a0);
            a1 = fmaf(wv, __uint_as_float(u[q].x & 0xffff0000u), a1);
            a2 = fmaf(wv, __uint_as_float(u[q].y << 16), a2);
            a3 = fmaf(wv, __uint_as_float(u[q].y & 0xffff0000u), a3);
        }
        #pragma unroll
        for (int q = 0; q < 16; ++q) u[q] = v[q];
    }

    const float bb = bm[o];
    a0 = fmaxf(a0 + bb, 0.f);
    a1 = fmaxf(a1 + bb, 0.f);
    a2 = fmaxf(a2 + bb, 0.f);
    a3 = fmaxf(a3 + bb, 0.f);

    bf16x4 ov;
    ov[0] = (short)f2bf(a0); ov[1] = (short)f2bf(a1);
    ov[2] = (short)f2bf(a2); ov[3] = (short)f2bf(a3);
    *(bf16x4*)&outv[(size_t)o * B_SZ + bOff] = ov;
}

// ---------------------------------------------------------------------------
// Reduce split-K partials + bias: y[b,n] = sum_s P[s,b,n] + b_out[n]
// ---------------------------------------------------------------------------
__global__ __launch_bounds__(256)
void reduce_out(const float* __restrict__ P,
                const float* __restrict__ b_out,
                float* __restrict__ y)
{
    const int i = blockIdx.x * 256 + threadIdx.x;
    if (i >= (B_SZ * N_OUT) / 4) return;
    const int e = i * 4;
    const int b = e / N_OUT;
    const int n = e - b * N_OUT;                  // multiple of 4

    float4 acc = *(const float4*)&b_out[n];
    #pragma unroll
    for (int s = 0; s < SPLITK; ++s) {
        const float4 p = *(const float4*)&P[((size_t)s * B_SZ + b) * N_OUTP + n];
        acc.x += p.x; acc.y += p.y; acc.z += p.z; acc.w += p.w;
    }
    *(float4*)&y[e] = acc;
}

// ---------------------------------------------------------------------------
extern "C" void kernel_launch(void* const* d_in, const int* in_sizes, int n_in,
                              void* d_out, int out_size, void* d_ws, size_t ws_size,
                              hipStream_t stream)
{
    const float* x      = (const float*)d_in[0];  // (512, 1024)
    const float* W_in   = (const float*)d_in[1];  // (8192, 1024)
    const float* b_in   = (const float*)d_in[2];  // (8192)
    const float* W_mid  = (const float*)d_in[3];  // (2, 8192, 64)
    const float* b_mid  = (const float*)d_in[4];  // (2, 8192)
    const float* W_out  = (const float*)d_in[5];  // (1000, 8192)
    const float* b_out  = (const float*)d_in[6];  // (1000)
    const int*   indx   = (const int*)d_in[7];    // (8192, 64)

    float* y = (float*)d_out;                     // (512, 1000)

    // ---- workspace layout ----
    char* w = (char*)d_ws;
    unsigned short* hA = (unsigned short*)w; w += (size_t)N_MID * B_SZ * 2;  // 8.4 MB
    unsigned short* hB = (unsigned short*)w; w += (size_t)N_MID * B_SZ * 2;  // 8.4 MB
    unsigned short* hC = (unsigned short*)w; w += (size_t)N_MID * B_SZ * 2;  // 8.4 MB
    float* P    = (float*)w;                 w += (size_t)SPLITK * B_SZ * N_OUTP * 4; // 16.8 MB
    short* Wb   = (short*)w;                 w += (size_t)N_MID * N_IN * 2;  // 16.8 MB (W_in; reused for W_out)
    short* xb   = (short*)w;                 w += (size_t)B_SZ * N_IN * 2;   // 1.05 MB
    short* htb  = (short*)w;                 w += (size_t)B_SZ * N_MID * 2;  // 8.4 MB
    // total ~68.3 MB

    const int KT1 = N_IN / 32;    // 32 k-frags (GEMM1)
    const int KT3 = N_MID / 32;   // 256 k-frags (GEMM3)

    // 1) conversions for GEMM1
    {
        const int nf = (N_MID / 16) * KT1;   // 16384
        conv_nt<<<nf / 4, 256, 0, stream>>>(W_in, N_MID, N_IN, KT1, Wb, nf);
    }
    {
        const int nf = (B_SZ / 16) * KT1;    // 1024
        conv_nt<<<nf / 4, 256, 0, stream>>>(x, B_SZ, N_IN, KT1, xb, nf);
    }

    // 2) GEMM1: hA[m, b] = relu(W_in x^T + b_in)  (bf16 out, XCD-swizzled)
    gemm_bf16<1, true, true><<<512, 256, 0, stream>>>(Wb, xb, b_in, hA,
                                                      KT1, 0, B_SZ);

    // 3) condensed layers (bf16 gather, chunked, software-pipelined)
    condensed_relu_g<<<NCHUNK * 2048, 256, 0, stream>>>(hA, indx, W_mid, b_mid, hB);
    condensed_relu_g<<<NCHUNK * 2048, 256, 0, stream>>>(hB, indx,
                                              W_mid + (size_t)N_MID * FANIN,
                                              b_mid + N_MID, hC);

    // 4) conversions for GEMM3: hC^T (bit-transpose) and W_out (padded rows)
    {
        const int nf = (B_SZ / 16) * KT3;    // 8192
        conv_t_bf16<<<nf / 4, 256, 0, stream>>>(hC, B_SZ, KT3, htb, nf);
    }
    {
        const int nf = (N_OUTP / 16) * KT3;  // 16384
        conv_nt<<<nf / 4, 256, 0, stream>>>(W_out, N_OUT, N_MID, KT3, Wb, nf);
    }

    // 5) GEMM3 split-K (512 blocks = 8 ln x 8 splits x 8 lm)
    gemm_bf16<3, false, false><<<512, 256, 0, stream>>>(htb, Wb, nullptr, P,
                                                        KT3, (size_t)B_SZ * N_OUTP,
                                                        N_OUTP);

    // 6) reduce + bias
    reduce_out<<<(B_SZ * N_OUT / 4 + 255) / 256, 256, 0, stream>>>(P, b_out, y);
}

// Round 13
// 232.907 us; speedup vs baseline: 2.5297x; 1.0111x over previous
//
#include <hip/hip_runtime.h>

#define B_SZ   512
#define N_IN   1024
#define N_MID  8192
#define N_OUT  1000
#define N_OUTP 1024          // padded
#define FANIN  64
#define SPLITK 8
#define NCHUNK 2
#define BCH    (B_SZ / NCHUNK)   // 256 cols -> 8192*256*2B = 4 MB bf16 slice == one XCD L2

typedef __attribute__((ext_vector_type(8))) short bf16x8;
typedef __attribute__((ext_vector_type(4))) short bf16x4;
typedef __attribute__((ext_vector_type(4))) float f32x4;

static __device__ __forceinline__ unsigned short f2bf(float f) {
    unsigned u = __float_as_uint(f);
    unsigned r = u + 0x7FFF + ((u >> 16) & 1);   // round-to-nearest-even
    return (unsigned short)(r >> 16);
}
static __device__ __forceinline__ float bf2f(unsigned short h) {
    return __uint_as_float(((unsigned)h) << 16);
}

// ---------------------------------------------------------------------------
// Convert fp32 (R x K, row-major, K-inner) -> bf16 MFMA fragments.
// Fragment (mt,kt): lane l holds (m = mt*16 + (l&15), k = kt*32 + (l>>4)*8+j).
// Rows >= R zero-padded.
// ---------------------------------------------------------------------------
__global__ __launch_bounds__(256)
void conv_nt(const float* __restrict__ src, int R, int K, int KT,
             short* __restrict__ dst, int nfrag)
{
    const int wid = threadIdx.x >> 6, lane = threadIdx.x & 63;
    const int fid = blockIdx.x * 4 + wid;
    if (fid >= nfrag) return;
    const int mt = fid / KT, kt = fid - mt * KT;
    const int m = mt * 16 + (lane & 15);
    const int k = kt * 32 + (lane >> 4) * 8;

    float v[8];
    if (m < R) {
        const float4 a = *(const float4*)(src + (size_t)m * K + k);
        const float4 b = *(const float4*)(src + (size_t)m * K + k + 4);
        v[0]=a.x; v[1]=a.y; v[2]=a.z; v[3]=a.w;
        v[4]=b.x; v[5]=b.y; v[6]=b.z; v[7]=b.w;
    } else {
        #pragma unroll
        for (int j = 0; j < 8; ++j) v[j] = 0.f;
    }
    bf16x8 vh;
    #pragma unroll
    for (int j = 0; j < 8; ++j) vh[j] = (short)f2bf(v[j]);
    *(bf16x8*)(dst + (size_t)fid * 512 + lane * 8) = vh;
}

// ---------------------------------------------------------------------------
// Transpose bf16 (K x Bcols, k-major) -> fragments of src^T (Bcols x K).
// ---------------------------------------------------------------------------
__global__ __launch_bounds__(256)
void conv_t_bf16(const unsigned short* __restrict__ src, int Bc, int KT,
                 short* __restrict__ dst, int nfrag)
{
    const int wid = threadIdx.x >> 6, lane = threadIdx.x & 63;
    const int fid = blockIdx.x * 4 + wid;
    if (fid >= nfrag) return;
    const int bt = fid / KT, kt = fid - bt * KT;
    const int b = bt * 16 + (lane & 15);
    const int k = kt * 32 + (lane >> 4) * 8;

    bf16x8 v;
    #pragma unroll
    for (int j = 0; j < 8; ++j)
        v[j] = (short)src[(size_t)(k + j) * Bc + b];
    *(bf16x8*)(dst + (size_t)fid * 512 + lane * 8) = v;
}

// ---------------------------------------------------------------------------
// Fragment-direct bf16 MFMA GEMM, XCD-swizzled 1D grid of 512 blocks.
// D[m,n] = sum_k A[m,k]*B[n,k] (K-inner pre-swizzled frags).
// Block: 4 waves in 2x2; block tile 64(m) x 128(n); wave tile 32x64
// (acc[2][4] -> 0.75 KB fragment bytes per MFMA).
// MODE 1 (GEMM1): per-XCD A m-slice 2.1 MB + B 1 MB resident in L2.
// MODE 3 (GEMM3 split-K): per-XCD B n-slice 2.1 MB resident.
// ---------------------------------------------------------------------------
template<int MODE, bool RELU, bool OBF16>
__global__ __launch_bounds__(256)
void gemm_bf16(const short* __restrict__ A, const short* __restrict__ Bm,
               const float* __restrict__ bias,   // per-m, only when RELU
               void* __restrict__ Cv,
               int KT, size_t csliceStride, int ldc)
{
    const int lane = threadIdx.x & 63;
    const int wid  = threadIdx.x >> 6;
    const int wm = wid & 1, wn = wid >> 1;
    const int f = blockIdx.x;

    int lm, ln, ktBeg, ktEnd;
    size_t cbase = 0;
    if (MODE == 1) {
        const int xcd = f & 7, i = f >> 3;
        ln = i & 3;
        lm = xcd * 16 + (i >> 2);
        ktBeg = 0; ktEnd = KT;
    } else {
        ln = f & 7;
        const int s = (f >> 3) & 7;
        lm = f >> 6;
        ktBeg = s * 32; ktEnd = ktBeg + 32;
        cbase = (size_t)s * csliceStride;
    }
    const int mt0 = lm * 4 + wm * 2;
    const int nt0 = ln * 8 + wn * 4;

    f32x4 acc[2][4] = {};
    const size_t laneOff = (size_t)lane * 8;

    #pragma unroll 4
    for (int kt = ktBeg; kt < ktEnd; ++kt) {
        bf16x8 a[2], b[4];
        #pragma unroll
        for (int i = 0; i < 2; ++i)
            a[i] = *(const bf16x8*)(A + ((size_t)(mt0 + i) * KT + kt) * 512 + laneOff);
        #pragma unroll
        for (int j = 0; j < 4; ++j)
            b[j] = *(const bf16x8*)(Bm + ((size_t)(nt0 + j) * KT + kt) * 512 + laneOff);
        #pragma unroll
        for (int i = 0; i < 2; ++i)
            #pragma unroll
            for (int j = 0; j < 4; ++j)
                acc[i][j] = __builtin_amdgcn_mfma_f32_16x16x32_bf16(a[i], b[j], acc[i][j], 0, 0, 0);
    }

    // C/D layout: col = lane&15, row = (lane>>4)*4 + r   [measured m89/m91]
    const int col = lane & 15;
    const int rb  = (lane >> 4) * 4;
    #pragma unroll
    for (int i = 0; i < 2; ++i) {
        #pragma unroll
        for (int r = 0; r < 4; ++r) {
            const int m = (mt0 + i) * 16 + rb + r;
            float bv = 0.f;
            if (RELU) bv = bias[m];
            #pragma unroll
            for (int j = 0; j < 4; ++j) {
                const int n = (nt0 + j) * 16 + col;
                float v = acc[i][j][r] + bv;
                if (RELU) v = fmaxf(v, 0.f);
                if (OBF16)
                    ((unsigned short*)Cv)[cbase + (size_t)m * ldc + n] = f2bf(v);
                else
                    ((float*)Cv)[cbase + (size_t)m * ldc + n] = v;
            }
        }
    }
}

// ---------------------------------------------------------------------------
// Condensed layer, bf16 gather, B-chunked for L2 residency. LDS-FREE:
// lane L holds (idx[o,L], W[o,L]) in registers; per-f broadcast via
// v_readlane with compile-time lane index (full unroll). Removes the 128
// ds_read_b32/wave that were ~50% of the LDS-pipe-limited runtime in
// rounds 4/8/11/12 (all flat ~40-43 us). Load pipelining (4x16) retained.
// ---------------------------------------------------------------------------
__global__ __launch_bounds__(256)
void condensed_relu_g(const unsigned short* __restrict__ h,
                      const int*   __restrict__ idx,
                      const float* __restrict__ W,
                      const float* __restrict__ bm,
                      unsigned short* __restrict__ outv)
{
    const int w     = threadIdx.x >> 6;
    const int lane  = threadIdx.x & 63;
    const int chunk = blockIdx.x >> 11;                 // 2048 blocks/chunk
    const int o     = ((blockIdx.x & 2047) << 2) + w;
    const int bOff  = chunk * BCH + lane * 4;

    // per-lane register copy of this wave's idx/W row (coalesced 256 B/wave)
    const int      idxReg = idx[(size_t)o * FANIN + lane];
    const unsigned wReg   = __float_as_uint(W[(size_t)o * FANIN + lane]);

    const unsigned short* hbase = h + bOff;   // per-lane, loop-invariant

    float a0 = 0.f, a1 = 0.f, a2 = 0.f, a3 = 0.f;

    uint2 u[16];
    #pragma unroll
    for (int q = 0; q < 16; ++q) {
        const int j = __builtin_amdgcn_readlane(idxReg, q);
        u[q] = *(const uint2*)(hbase + (size_t)j * B_SZ);
    }

    #pragma unroll
    for (int fb = 0; fb < 4; ++fb) {
        uint2 v[16];
        if (fb < 3) {
            #pragma unroll
            for (int q = 0; q < 16; ++q) {
                const int j = __builtin_amdgcn_readlane(idxReg, (fb + 1) * 16 + q);
                v[q] = *(const uint2*)(hbase + (size_t)j * B_SZ);
            }
        }
        #pragma unroll
        for (int q = 0; q < 16; ++q) {
            const float wv = __uint_as_float(
                __builtin_amdgcn_readlane(wReg, fb * 16 + q));
            a0 = fmaf(wv, __uint_as_float(u[q].x << 16), a0);
            a1 = fmaf(wv, __uint_as_float(u[q].x & 0xffff0000u), a1);
            a2 = fmaf(wv, __uint_as_float(u[q].y << 16), a2);
            a3 = fmaf(wv, __uint_as_float(u[q].y & 0xffff0000u), a3);
        }
        #pragma unroll
        for (int q = 0; q < 16; ++q) u[q] = v[q];
    }

    const float bb = bm[o];
    a0 = fmaxf(a0 + bb, 0.f);
    a1 = fmaxf(a1 + bb, 0.f);
    a2 = fmaxf(a2 + bb, 0.f);
    a3 = fmaxf(a3 + bb, 0.f);

    bf16x4 ov;
    ov[0] = (short)f2bf(a0); ov[1] = (short)f2bf(a1);
    ov[2] = (short)f2bf(a2); ov[3] = (short)f2bf(a3);
    *(bf16x4*)&outv[(size_t)o * B_SZ + bOff] = ov;
}

// ---------------------------------------------------------------------------
// Reduce split-K partials + bias: y[b,n] = sum_s P[s,b,n] + b_out[n]
// ---------------------------------------------------------------------------
__global__ __launch_bounds__(256)
void reduce_out(const float* __restrict__ P,
                const float* __restrict__ b_out,
                float* __restrict__ y)
{
    const int i = blockIdx.x * 256 + threadIdx.x;
    if (i >= (B_SZ * N_OUT) / 4) return;
    const int e = i * 4;
    const int b = e / N_OUT;
    const int n = e - b * N_OUT;                  // multiple of 4

    float4 acc = *(const float4*)&b_out[n];
    #pragma unroll
    for (int s = 0; s < SPLITK; ++s) {
        const float4 p = *(const float4*)&P[((size_t)s * B_SZ + b) * N_OUTP + n];
        acc.x += p.x; acc.y += p.y; acc.z += p.z; acc.w += p.w;
    }
    *(float4*)&y[e] = acc;
}

// ---------------------------------------------------------------------------
extern "C" void kernel_launch(void* const* d_in, const int* in_sizes, int n_in,
                              void* d_out, int out_size, void* d_ws, size_t ws_size,
                              hipStream_t stream)
{
    const float* x      = (const float*)d_in[0];  // (512, 1024)
    const float* W_in   = (const float*)d_in[1];  // (8192, 1024)
    const float* b_in   = (const float*)d_in[2];  // (8192)
    const float* W_mid  = (const float*)d_in[3];  // (2, 8192, 64)
    const float* b_mid  = (const float*)d_in[4];  // (2, 8192)
    const float* W_out  = (const float*)d_in[5];  // (1000, 8192)
    const float* b_out  = (const float*)d_in[6];  // (1000)
    const int*   indx   = (const int*)d_in[7];    // (8192, 64)

    float* y = (float*)d_out;                     // (512, 1000)

    // ---- workspace layout ----
    char* w = (char*)d_ws;
    unsigned short* hA = (unsigned short*)w; w += (size_t)N_MID * B_SZ * 2;  // 8.4 MB
    unsigned short* hB = (unsigned short*)w; w += (size_t)N_MID * B_SZ * 2;  // 8.4 MB
    unsigned short* hC = (unsigned short*)w; w += (size_t)N_MID * B_SZ * 2;  // 8.4 MB
    float* P    = (float*)w;                 w += (size_t)SPLITK * B_SZ * N_OUTP * 4; // 16.8 MB
    short* Wb   = (short*)w;                 w += (size_t)N_MID * N_IN * 2;  // 16.8 MB (W_in; reused for W_out)
    short* xb   = (short*)w;                 w += (size_t)B_SZ * N_IN * 2;   // 1.05 MB
    short* htb  = (short*)w;                 w += (size_t)B_SZ * N_MID * 2;  // 8.4 MB
    // total ~68.3 MB

    const int KT1 = N_IN / 32;    // 32 k-frags (GEMM1)
    const int KT3 = N_MID / 32;   // 256 k-frags (GEMM3)

    // 1) conversions for GEMM1
    {
        const int nf = (N_MID / 16) * KT1;   // 16384
        conv_nt<<<nf / 4, 256, 0, stream>>>(W_in, N_MID, N_IN, KT1, Wb, nf);
    }
    {
        const int nf = (B_SZ / 16) * KT1;    // 1024
        conv_nt<<<nf / 4, 256, 0, stream>>>(x, B_SZ, N_IN, KT1, xb, nf);
    }

    // 2) GEMM1: hA[m, b] = relu(W_in x^T + b_in)  (bf16 out, XCD-swizzled)
    gemm_bf16<1, true, true><<<512, 256, 0, stream>>>(Wb, xb, b_in, hA,
                                                      KT1, 0, B_SZ);

    // 3) condensed layers (bf16 gather, chunked, LDS-free readlane broadcast)
    condensed_relu_g<<<NCHUNK * 2048, 256, 0, stream>>>(hA, indx, W_mid, b_mid, hB);
    condensed_relu_g<<<NCHUNK * 2048, 256, 0, stream>>>(hB, indx,
                                              W_mid + (size_t)N_MID * FANIN,
                                              b_mid + N_MID, hC);

    // 4) conversions for GEMM3: hC^T (bit-transpose) and W_out (padded rows)
    {
        const int nf = (B_SZ / 16) * KT3;    // 8192
        conv_t_bf16<<<nf / 4, 256, 0, stream>>>(hC, B_SZ, KT3, htb, nf);
    }
    {
        const int nf = (N_OUTP / 16) * KT3;  // 16384
        conv_nt<<<nf / 4, 256, 0, stream>>>(W_out, N_OUT, N_MID, KT3, Wb, nf);
    }

    // 5) GEMM3 split-K (512 blocks = 8 ln x 8 splits x 8 lm)
    gemm_bf16<3, false, false><<<512, 256, 0, stream>>>(htb, Wb, nullptr, P,
                                                        KT3, (size_t)B_SZ * N_OUTP,
                                                        N_OUTP);

    // 6) reduce + bias
    reduce_out<<<(B_SZ * N_OUT / 4 + 255) / 256, 256, 0, stream>>>(P, b_out, y);
}